// Round 5
// baseline (2904.968 us; speedup 1.0000x reference)
//
#include <hip/hip_runtime.h>
#include <cstdint>
#include <cstddef>

#define B_   64
#define S_   49
#define T_   32
#define D_   512
#define V_   32000
#define G3   1536
#define NBLK 256

typedef short s16x8 __attribute__((ext_vector_type(8)));
typedef float v4f   __attribute__((ext_vector_type(4)));
typedef _Float16 f16;
typedef _Float16 f16x8 __attribute__((ext_vector_type(8)));

__device__ __forceinline__ float sigm(float x) { return 1.f / (1.f + __expf(-x)); }

// ---------------- fp32 -> f16 conversion (8 elems/thread) ----------------
__global__ __launch_bounds__(256) void k_cvt16(const float* __restrict__ in,
                                               f16* __restrict__ out) {
  int i = (blockIdx.x * 256 + threadIdx.x) * 8;
  float4 a = *(const float4*)(in + i);
  float4 b = *(const float4*)(in + i + 4);
  f16x8 o;
  o[0] = (f16)a.x; o[1] = (f16)a.y; o[2] = (f16)a.z; o[3] = (f16)a.w;
  o[4] = (f16)b.x; o[5] = (f16)b.y; o[6] = (f16)b.z; o[7] = (f16)b.w;
  *(f16x8*)(out + i) = o;
}

// ---------------- embedding gather + active mask ----------------
__global__ __launch_bounds__(128) void k_embed(const float* __restrict__ emb,
    const int* __restrict__ seq, const int* __restrict__ length,
    float* __restrict__ x_embed, float* __restrict__ actmask) {
  int m = blockIdx.x;
  int t = m >> 6, b = m & 63;
  int idx = seq[b * T_ + t];
  const float4* src = (const float4*)(emb + (size_t)idx * D_);
  float4* dst = (float4*)(x_embed + (size_t)m * D_);
  dst[threadIdx.x] = src[threadIdx.x];
  if (threadIdx.x == 0) actmask[b * T_ + t] = (t < length[b]) ? 1.f : 0.f;
}

// ---------------- feats mean + scope init ----------------
__global__ __launch_bounds__(256) void k_hmean(const float* __restrict__ feats,
    float* __restrict__ hmean, float* __restrict__ scope) {
  int b = blockIdx.x, tid = threadIdx.x;
  for (int e = tid; e < D_; e += 256) {
    float s = 0.f;
    for (int si = 0; si < S_; ++si) s += feats[((size_t)b * S_ + si) * D_ + e];
    hmean[b * D_ + e] = s * (1.f / 49.f);
  }
  if (tid < S_) scope[b * S_ + tid] = 1.f;
}

// ---------------- generic fp32 GEMM: C[M,N] = X[M,K] @ W[N,ldw].T + bias ----------------
__global__ __launch_bounds__(256) void k_gemm_f32(
    float* __restrict__ C, const float* __restrict__ X, const float* __restrict__ W,
    const float* __restrict__ bias, int N, int K, int ldw) {
  __shared__ __align__(16) float XsT[32][68];
  __shared__ __align__(16) float WsT[32][68];
  const int nbase = blockIdx.x * 64, mbase = blockIdx.y * 64;
  const int tid = threadIdx.x;
  const int lr = tid >> 2;
  const int lk = (tid & 3) * 8;
  const int ty = tid >> 4, tx = tid & 15;
  float acc[4][4] = {};
  for (int k0 = 0; k0 < K; k0 += 32) {
    {
      const float* xs = X + (size_t)(mbase + lr) * K + k0 + lk;
      const float* wsrc = W + (size_t)(nbase + lr) * ldw + k0 + lk;
      float4 x0 = *(const float4*)xs, x1 = *(const float4*)(xs + 4);
      float4 w0 = *(const float4*)wsrc, w1 = *(const float4*)(wsrc + 4);
      XsT[lk + 0][lr] = x0.x; XsT[lk + 1][lr] = x0.y; XsT[lk + 2][lr] = x0.z; XsT[lk + 3][lr] = x0.w;
      XsT[lk + 4][lr] = x1.x; XsT[lk + 5][lr] = x1.y; XsT[lk + 6][lr] = x1.z; XsT[lk + 7][lr] = x1.w;
      WsT[lk + 0][lr] = w0.x; WsT[lk + 1][lr] = w0.y; WsT[lk + 2][lr] = w0.z; WsT[lk + 3][lr] = w0.w;
      WsT[lk + 4][lr] = w1.x; WsT[lk + 5][lr] = w1.y; WsT[lk + 6][lr] = w1.z; WsT[lk + 7][lr] = w1.w;
    }
    __syncthreads();
    #pragma unroll
    for (int kk = 0; kk < 32; ++kk) {
      float4 a4 = *(const float4*)&XsT[kk][ty * 4];
      float4 w4 = *(const float4*)&WsT[kk][tx * 4];
      float av[4] = {a4.x, a4.y, a4.z, a4.w};
      float wv[4] = {w4.x, w4.y, w4.z, w4.w};
      #pragma unroll
      for (int i = 0; i < 4; ++i)
        #pragma unroll
        for (int j = 0; j < 4; ++j)
          acc[i][j] = fmaf(av[i], wv[j], acc[i][j]);
    }
    __syncthreads();
  }
  #pragma unroll
  for (int i = 0; i < 4; ++i) {
    int m = mbase + ty * 4 + i;
    int n = nbase + tx * 4;
    float4 o;
    o.x = acc[i][0] + bias[n + 0];
    o.y = acc[i][1] + bias[n + 1];
    o.z = acc[i][2] + bias[n + 2];
    o.w = acc[i][3] + bias[n + 3];
    *(float4*)&C[(size_t)m * N + n] = o;
  }
}

// ---------------- pack kernels (phase A) ----------------
__global__ __launch_bounds__(256) void k_packW(
    const float* __restrict__ Wda, const float* __restrict__ Wbe,
    const float* __restrict__ Whh, const float* __restrict__ Wih,
    f16* __restrict__ Wp1, f16* __restrict__ Wp2) {
  int K = blockIdx.x, tid = threadIdx.x;
  for (int idx = tid; idx < 5120; idx += 256) {
    int s = idx >> 9, e = idx & 511;
    float v;
    if (s < 2)      v = Wda[(size_t)(2 * K + s) * D_ + e];
    else if (s < 4) v = Wbe[(size_t)(2 * K + s - 2) * D_ + e];
    else { int g = (s - 4) >> 1, jj = (s - 4) & 1;
           v = Whh[(size_t)(g * 512 + 2 * K + jj) * D_ + e]; }
    Wp1[(size_t)K * 5120 + idx] = (f16)v;
  }
  for (int idx = tid; idx < 3072; idx += 256) {
    int s = idx >> 9, e = idx & 511;
    int g = s >> 1, jj = s & 1;
    float v = Wih[(size_t)(g * 512 + 2 * K + jj) * 1024 + 512 + e];
    Wp2[(size_t)K * 3072 + idx] = (f16)v;
  }
}

__global__ __launch_bounds__(256) void k_packF(
    const float* __restrict__ feats, const float* __restrict__ att1,
    const float* __restrict__ h0,
    f16* __restrict__ feats16, f16* __restrict__ att116, f16* __restrict__ h16) {
  const int NF = B_ * S_ * D_;
  for (size_t i = blockIdx.x * 256 + threadIdx.x; i < 2 * NF + B_ * D_;
       i += (size_t)gridDim.x * 256) {
    if (i < NF)           feats16[i] = (f16)feats[i];
    else if (i < 2 * NF)  att116[i - NF] = (f16)att1[i - NF];
    else                  h16[i - 2 * NF] = (f16)h0[i - 2 * NF];
  }
}

__global__ __launch_bounds__(256) void k_packG(
    const float* __restrict__ gi_embed, float* __restrict__ gi_pack) {
  for (size_t i = blockIdx.x * 256 + threadIdx.x; i < (size_t)T_ * 256 * 64 * 8;
       i += (size_t)gridDim.x * 256) {
    int slot = i & 7;
    int b = (i >> 3) & 63;
    int K = (i >> 9) & 255;
    int t = i >> 17;
    float v = 0.f;
    if (slot < 6) {
      int g = slot >> 1, jj = slot & 1;
      v = gi_embed[((size_t)t * 64 + b) * G3 + g * 512 + 2 * K + jj];
    }
    gi_pack[i] = v;
  }
}

// -------- flag-based sync (R5): no contended RMW --------
// Writer: one release-store to its OWN slot. Waiters: n threads poll n dense
// flags in parallel (one IC round-trip per round) + block AND-reduce.
// R4's contended fetch_add (576 serialized RMW/step = ~70us/step) is gone.
__device__ __forceinline__ void wait_flags(const int* __restrict__ flags, int n,
                                           int target, int tid, int* ok4) {
  for (;;) {
    bool ok = true;
    if (tid < n)
      ok = __hip_atomic_load(flags + tid, __ATOMIC_RELAXED,
                             __HIP_MEMORY_SCOPE_AGENT) >= target;
    bool wok = __all(ok);
    if ((tid & 63) == 0) ok4[tid >> 6] = wok ? 1 : 0;
    __syncthreads();
    bool done = ok4[0] && ok4[1] && ok4[2] && ok4[3];
    __syncthreads();
    if (done) break;
    __builtin_amdgcn_s_sleep(4);
  }
  __threadfence();   // order subsequent data loads after flag observation
  __syncthreads();
}

__device__ __forceinline__ void set_flag(int* slot, int val, int tid) {
  __syncthreads();               // drains this block's stores (vmcnt before barrier)
  if (tid == 0) {
    __threadfence();
    __hip_atomic_store(slot, val, __ATOMIC_RELEASE, __HIP_MEMORY_SCOPE_AGENT);
  }
}

// ---------------- persistent recurrence: LDS-resident weights + flag sync ----------------
__global__ __launch_bounds__(256, 1) void k_recur(
    const f16* __restrict__ Wp1, const f16* __restrict__ Wp2,
    const f16* __restrict__ att116, const f16* __restrict__ feats16,
    const float* __restrict__ gi_pack,
    const float* __restrict__ b_da, const float* __restrict__ b_beta,
    const float* __restrict__ b_hh,
    const float* __restrict__ W_fa, const float* __restrict__ b_fa,
    const int* __restrict__ length,
    f16* __restrict__ h16, f16* __restrict__ xg16,
    float* __restrict__ att2g, float* __restrict__ scope,
    float* __restrict__ alphas, f16* __restrict__ Hbuf,
    int* __restrict__ flags) {
  __shared__ __align__(16) uint4 hs[4096];      // 64KB: h or xg staged, swizzled
  __shared__ __align__(16) uint4 W1[1024];      // 16KB
  __shared__ __align__(16) uint4 W2[1024];      // 16KB
  __shared__ float gh_lds[64][6];
  __shared__ float gix_lds[64][6];
  __shared__ float att2_s[512];
  __shared__ float gate_s[512];
  __shared__ float att_s[64];
  __shared__ float alpha_s[64];
  __shared__ int ok4[4];

  const int K = blockIdx.x, tid = threadIdx.x;
  const int w = tid >> 6, l = tid & 63;
  const int lm = l & 15, c4 = l >> 4;
  int* flagA = flags;          // [256] att2g/gh ready
  int* flagB = flags + 256;    // [64]  xg ready
  int* flagC = flags + 512;    // [256] h(t+1) ready

  // stage LDS-resident weight slices (once)
  {
    const uint4* s1 = (const uint4*)(Wp1 + (size_t)K * 5120);
    const uint4* s2 = (const uint4*)(Wp2 + (size_t)K * 3072);
    #pragma unroll
    for (int i = 0; i < 3; ++i) {
      int g = i * 256 + tid;
      if (g < 640) { int s = g >> 6, c = g & 63; W1[s * 64 + (c ^ (s & 7))] = s1[g]; }
    }
    #pragma unroll
    for (int i = 0; i < 2; ++i) {
      int g = i * 256 + tid;
      if (g < 384) { int s = g >> 6, c = g & 63; W2[s * 64 + (c ^ (s & 7))] = s2[g]; }
    }
  }
  const int lenP2 = (K < 64) ? length[K] : 0;
  const float bfa0 = b_fa[0];
  int   lb = 0; float bhr = 0.f, bhz = 0.f, bhn = 0.f;
  if (tid < 128) {
    int b = tid >> 1, jj = tid & 1;
    lb = length[b];
    bhr = b_hh[0 * 512 + 2 * K + jj];
    bhz = b_hh[1 * 512 + 2 * K + jj];
    bhn = b_hh[2 * 512 + 2 * K + jj];
  }
  __syncthreads();

  for (int t = 0; t < T_; ++t) {
    // ---- wait h(t) ready; stage into LDS (swizzled) ----
    if (t) wait_flags(flagC, 256, t, tid, ok4);
    {
      const uint4* src = (const uint4*)h16;
      #pragma unroll
      for (int i = 0; i < 16; ++i) {
        int g = i * 256 + tid;
        int b = g >> 6, c = g & 63;
        hs[b * 64 + (c ^ (b & 7))] = src[g];
      }
    }
    __syncthreads();
    // ---- matvec1: [64,512]@[512,16] -> att2(4) | gh(6) ----
    {
      v4f acc = {0.f, 0.f, 0.f, 0.f};
      int bb = w * 16 + lm;
      #pragma unroll
      for (int kt = 0; kt < 16; ++kt) {
        int ca = kt * 4 + c4;
        f16x8 a = __builtin_bit_cast(f16x8, hs[bb * 64 + (ca ^ (bb & 7))]);
        f16x8 bf = __builtin_bit_cast(f16x8, W1[lm * 64 + (ca ^ (lm & 7))]);
        acc = __builtin_amdgcn_mfma_f32_16x16x32_f16(a, bf, acc, 0, 0, 0);
      }
      #pragma unroll
      for (int r = 0; r < 4; ++r) {
        int b = w * 16 + c4 * 4 + r;
        if (lm < 4)       att2g[b * 1024 + K * 4 + lm] = acc[r];
        else if (lm < 10) gh_lds[b][lm - 4] = acc[r];
      }
    }
    set_flag(flagA + K, t + 1, tid);
    // ---- P2: attention (blocks 0..63, batch b=K) ----
    if (K < 64) {
      wait_flags(flagA, 256, t + 1, tid, ok4);
      int b = K;
      bool act = t < lenP2;
      for (int a = tid; a < 512; a += 256) {
        float v1 = att2g[b * 1024 + 4 * (a >> 1) + (a & 1)];
        float v2 = att2g[b * 1024 + 4 * (a >> 1) + 2 + (a & 1)];
        att2_s[a] = v1 + b_da[a];
        gate_s[a] = sigm(v2 + b_beta[a]);
      }
      __syncthreads();
      int lane = tid & 63, wv = tid >> 6;
      for (int s = wv; s < S_; s += 4) {
        const f16x8* arow = (const f16x8*)(att116 + ((size_t)b * S_ + s) * D_);
        int a0 = lane * 8;
        f16x8 av = arow[lane];
        float p = 0.f;
        #pragma unroll
        for (int jx = 0; jx < 8; ++jx) {
          float v = (float)av[jx] + att2_s[a0 + jx];
          v = v > 0.f ? v : 0.f;
          p = fmaf(v, W_fa[a0 + jx], p);
        }
        #pragma unroll
        for (int off = 32; off > 0; off >>= 1) p += __shfl_xor(p, off, 64);
        if (lane == 0) att_s[s] = p + bfa0;
      }
      __syncthreads();
      if (tid < 64) {
        float x = (tid < S_) ? att_s[tid] : -1e30f;
        float m = x;
        #pragma unroll
        for (int off = 32; off > 0; off >>= 1) m = fmaxf(m, __shfl_xor(m, off, 64));
        float e = (tid < S_) ? __expf(x - m) : 0.f;
        float su = e;
        #pragma unroll
        for (int off = 32; off > 0; off >>= 1) su += __shfl_xor(su, off, 64);
        if (tid < S_) alpha_s[tid] = e / su;
      }
      __syncthreads();
      if (tid < S_) {
        float old = scope[b * S_ + tid], al = alpha_s[tid];
        alphas[((size_t)b * T_ + t) * S_ + tid] = act ? old * al : 0.f;
        scope[b * S_ + tid] = act ? old * (1.f - al) : old;
      }
      for (int e = tid; e < D_; e += 256) {
        float aw = 0.f;
        #pragma unroll 7
        for (int s = 0; s < S_; ++s)
          aw = fmaf(alpha_s[s], (float)feats16[((size_t)b * S_ + s) * D_ + e], aw);
        xg16[b * D_ + e] = (f16)(gate_s[e] * aw);
      }
      set_flag(flagB + K, t + 1, tid);
    }
    // ---- wait xg ready; stage into LDS ----
    wait_flags(flagB, 64, t + 1, tid, ok4);
    {
      const uint4* src = (const uint4*)xg16;
      #pragma unroll
      for (int i = 0; i < 16; ++i) {
        int g = i * 256 + tid;
        int b = g >> 6, c = g & 63;
        hs[b * 64 + (c ^ (b & 7))] = src[g];
      }
    }
    __syncthreads();
    // ---- matvec2: [64,512]@[512,16] -> gix(6) ----
    {
      v4f acc = {0.f, 0.f, 0.f, 0.f};
      int bb = w * 16 + lm;
      #pragma unroll
      for (int kt = 0; kt < 16; ++kt) {
        int ca = kt * 4 + c4;
        f16x8 a = __builtin_bit_cast(f16x8, hs[bb * 64 + (ca ^ (bb & 7))]);
        f16x8 bf = __builtin_bit_cast(f16x8, W2[lm * 64 + (ca ^ (lm & 7))]);
        acc = __builtin_amdgcn_mfma_f32_16x16x32_f16(a, bf, acc, 0, 0, 0);
      }
      #pragma unroll
      for (int r = 0; r < 4; ++r) {
        int b = w * 16 + c4 * 4 + r;
        if (lm < 6) gix_lds[b][lm] = acc[r];
      }
    }
    __syncthreads();
    // ---- pointwise GRU for own j-pair ----
    if (tid < 128) {
      int b = tid >> 1, jj = tid & 1;
      const float* gp = gi_pack + (((size_t)t * 256 + K) * 64 + b) * 8;
      float r = sigm(gix_lds[b][0 + jj] + gp[0 + jj] + gh_lds[b][0 + jj] + bhr);
      float z = sigm(gix_lds[b][2 + jj] + gp[2 + jj] + gh_lds[b][2 + jj] + bhz);
      float n = tanhf(gix_lds[b][4 + jj] + gp[4 + jj] + r * (gh_lds[b][4 + jj] + bhn));
      int j = 2 * K + jj;
      float hold = (float)h16[b * D_ + j];
      float hn = (1.f - z) * n + z * hold;
      bool act = t < lb;
      h16[b * D_ + j] = (f16)(act ? hn : hold);
      Hbuf[((size_t)b * T_ + t) * D_ + j] = (f16)hn;
    }
    set_flag(flagC + K, t + 1, tid);
  }
}

// ---------------- Phase C: out = actmask * (Hbuf @ Wout.T + b_out), f16 MFMA ----------------
__global__ __launch_bounds__(256) void k_outgemm(
    const f16* __restrict__ Hb, const f16* __restrict__ Wb,
    const float* __restrict__ b_out, const float* __restrict__ actmask,
    float* __restrict__ out) {
  __shared__ __align__(16) f16 As[128 * 32];
  __shared__ __align__(16) f16 Bs[128 * 32];
  const int bid = blockIdx.x;
  const int swz = (bid & 7) * 500 + (bid >> 3);
  const int mb = (swz & 15) * 128;
  const int nb = (swz >> 4) * 128;
  const int tid = threadIdx.x;
  const int l = tid & 63, w = tid >> 6;
  const int wr = w >> 1, wc = w & 1;
  const int lm = l & 15;
  const int kc = l >> 4;
  const int rchunk = (kc ^ ((lm >> 1) & 3)) * 8;
  v4f acc[4][4];
  #pragma unroll
  for (int mi = 0; mi < 4; ++mi)
    #pragma unroll
    for (int ni = 0; ni < 4; ++ni)
      acc[mi][ni] = (v4f){0.f, 0.f, 0.f, 0.f};

  for (int k0 = 0; k0 < 512; k0 += 32) {
    #pragma unroll
    for (int i = 0; i < 2; ++i) {
      int ch = i * 256 + tid;
      int row = ch >> 2, cq = ch & 3;
      int sc = (cq ^ ((row >> 1) & 3)) * 8;
      *(int4*)&As[row * 32 + sc] =
          *(const int4*)&Hb[(size_t)(mb + row) * 512 + k0 + cq * 8];
      *(int4*)&Bs[row * 32 + sc] =
          *(const int4*)&Wb[(size_t)(nb + row) * 512 + k0 + cq * 8];
    }
    __syncthreads();
    f16x8 af[4], bf[4];
    #pragma unroll
    for (int mi = 0; mi < 4; ++mi)
      af[mi] = *(const f16x8*)&As[(wr * 64 + mi * 16 + lm) * 32 + rchunk];
    #pragma unroll
    for (int ni = 0; ni < 4; ++ni)
      bf[ni] = *(const f16x8*)&Bs[(wc * 64 + ni * 16 + lm) * 32 + rchunk];
    #pragma unroll
    for (int mi = 0; mi < 4; ++mi)
      #pragma unroll
      for (int ni = 0; ni < 4; ++ni)
        acc[mi][ni] = __builtin_amdgcn_mfma_f32_16x16x32_f16(af[mi], bf[ni], acc[mi][ni], 0, 0, 0);
    __syncthreads();
  }
  #pragma unroll
  for (int ni = 0; ni < 4; ++ni) {
    int n = nb + wc * 64 + ni * 16 + lm;
    float bo = b_out[n];
    #pragma unroll
    for (int mi = 0; mi < 4; ++mi) {
      int m0 = mb + wr * 64 + mi * 16 + (l >> 4) * 4;
      #pragma unroll
      for (int r = 0; r < 4; ++r) {
        int m = m0 + r;
        out[(size_t)m * V_ + n] = actmask[m] * (acc[mi][ni][r] + bo);
      }
    }
  }
}

extern "C" void kernel_launch(void* const* d_in, const int* in_sizes, int n_in,
                              void* d_out, int out_size, void* d_ws, size_t ws_size,
                              hipStream_t stream) {
  const float* feats  = (const float*)d_in[0];
  const int*   seq    = (const int*)d_in[1];
  const int*   length = (const int*)d_in[2];
  const float* emb    = (const float*)d_in[3];
  const float* W_ih   = (const float*)d_in[4];
  const float* b_ih   = (const float*)d_in[5];
  const float* W_hh   = (const float*)d_in[6];
  const float* b_hh   = (const float*)d_in[7];
  const float* W_out  = (const float*)d_in[8];
  const float* b_out  = (const float*)d_in[9];
  const float* W_init = (const float*)d_in[10];
  const float* b_init = (const float*)d_in[11];
  const float* W_beta = (const float*)d_in[12];
  const float* b_beta = (const float*)d_in[13];
  const float* W_ea   = (const float*)d_in[14];
  const float* b_ea   = (const float*)d_in[15];
  const float* W_da   = (const float*)d_in[16];
  const float* b_da   = (const float*)d_in[17];
  const float* W_fa   = (const float*)d_in[18];
  const float* b_fa   = (const float*)d_in[19];

  float* out    = (float*)d_out;
  float* alphas = out + (size_t)B_ * T_ * V_;

  // ---- workspace layout ----
  float* ws = (float*)d_ws;
  int*   flags    = (int*)ws;        ws += 1024;          // A[256] B[64..] C[512..]
  float* h0       = ws;              ws += B_ * D_;
  float* hmean    = ws;              ws += B_ * D_;
  float* scope    = ws;              ws += 4096;
  float* actmask  = ws;              ws += B_ * T_;
  float* att2g    = ws;              ws += B_ * 1024;
  float* x_embed  = ws;              ws += (size_t)B_ * T_ * D_;
  float* gi_embed = ws;              ws += (size_t)B_ * T_ * G3;
  float* gi_pack  = ws;              ws += (size_t)T_ * 256 * 64 * 8;
  float* att1     = ws;              ws += (size_t)B_ * S_ * D_;
  f16* fp = (f16*)ws;
  f16* Woutb   = fp;  fp += (size_t)V_ * D_;
  f16* Hbuf    = fp;  fp += (size_t)B_ * T_ * D_;
  f16* Wp1     = fp;  fp += (size_t)256 * 5120;
  f16* Wp2     = fp;  fp += (size_t)256 * 3072;
  f16* feats16 = fp;  fp += (size_t)B_ * S_ * D_;
  f16* att116  = fp;  fp += (size_t)B_ * S_ * D_;
  f16* h16     = fp;  fp += B_ * D_;
  f16* xg16    = fp;  fp += B_ * D_;

  hipMemsetAsync(flags, 0, 4096, stream);

  // ---- Phase A ----
  k_cvt16<<<(V_ * D_) / 2048, 256, 0, stream>>>(W_out, Woutb);
  k_embed<<<B_ * T_, 128, 0, stream>>>(emb, seq, length, x_embed, actmask);
  k_hmean<<<B_, 256, 0, stream>>>(feats, hmean, scope);
  k_gemm_f32<<<dim3(8, 1), 256, 0, stream>>>(h0, hmean, W_init, b_init, 512, 512, 512);
  k_gemm_f32<<<dim3(8, 49), 256, 0, stream>>>(att1, feats, W_ea, b_ea, 512, 512, 512);
  k_gemm_f32<<<dim3(24, 32), 256, 0, stream>>>(gi_embed, x_embed, W_ih, b_ih, 1536, 512, 1024);
  k_packW<<<256, 256, 0, stream>>>(W_da, W_beta, W_hh, W_ih, Wp1, Wp2);
  k_packF<<<2048, 256, 0, stream>>>(feats, att1, h0, feats16, att116, h16);
  k_packG<<<2048, 256, 0, stream>>>(gi_embed, gi_pack);

  // ---- Phase B: persistent recurrence, flag-based sync ----
  k_recur<<<NBLK, 256, 0, stream>>>(Wp1, Wp2, att116, feats16, gi_pack,
      b_da, b_beta, b_hh, W_fa, b_fa, length,
      h16, xg16, att2g, scope, alphas, Hbuf, flags);

  // ---- Phase C ----
  k_outgemm<<<4000, 256, 0, stream>>>(Hbuf, Woutb, b_out, actmask, out);
}

// Round 6
// 1660.684 us; speedup vs baseline: 1.7493x; 1.7493x over previous
//
#include <hip/hip_runtime.h>
#include <cstdint>
#include <cstddef>

#define B_   64
#define S_   49
#define T_   32
#define D_   512
#define V_   32000
#define G3   1536
#define NBLK 256

typedef short s16x8 __attribute__((ext_vector_type(8)));
typedef float v4f   __attribute__((ext_vector_type(4)));
typedef _Float16 f16;
typedef _Float16 f16x8 __attribute__((ext_vector_type(8)));
typedef _Float16 f16x4 __attribute__((ext_vector_type(4)));

__device__ __forceinline__ float sigm(float x) { return 1.f / (1.f + __expf(-x)); }

// ---- agent-scope RELAXED atomics: coherent via IC, NO buffer_wbl2/buffer_inv ----
// (R4/R5 post-mortem: the ~25us/sync was the agent-scope __threadfence pair
//  = full per-XCD L2 writeback+invalidate. Relaxed atomic ld/st bypass to the
//  coherence point without cache maintenance; R5's polls proved remote
//  visibility of relaxed agent loads on this chip.)
__device__ __forceinline__ uint64_t ld_a64(const void* p) {
  return __hip_atomic_load((const uint64_t*)p, __ATOMIC_RELAXED, __HIP_MEMORY_SCOPE_AGENT);
}
__device__ __forceinline__ void st_a64(void* p, uint64_t v) {
  __hip_atomic_store((uint64_t*)p, v, __ATOMIC_RELAXED, __HIP_MEMORY_SCOPE_AGENT);
}
__device__ __forceinline__ uint32_t ld_a32(const void* p) {
  return __hip_atomic_load((const uint32_t*)p, __ATOMIC_RELAXED, __HIP_MEMORY_SCOPE_AGENT);
}
__device__ __forceinline__ void st_a32(void* p, uint32_t v) {
  __hip_atomic_store((uint32_t*)p, v, __ATOMIC_RELAXED, __HIP_MEMORY_SCOPE_AGENT);
}

// ---------------- fp32 -> f16 conversion ----------------
__global__ __launch_bounds__(256) void k_cvt16(const float* __restrict__ in,
                                               f16* __restrict__ out) {
  int i = (blockIdx.x * 256 + threadIdx.x) * 8;
  float4 a = *(const float4*)(in + i);
  float4 b = *(const float4*)(in + i + 4);
  f16x8 o;
  o[0] = (f16)a.x; o[1] = (f16)a.y; o[2] = (f16)a.z; o[3] = (f16)a.w;
  o[4] = (f16)b.x; o[5] = (f16)b.y; o[6] = (f16)b.z; o[7] = (f16)b.w;
  *(f16x8*)(out + i) = o;
}

// ---------------- embedding gather + active mask ----------------
__global__ __launch_bounds__(128) void k_embed(const float* __restrict__ emb,
    const int* __restrict__ seq, const int* __restrict__ length,
    float* __restrict__ x_embed, float* __restrict__ actmask) {
  int m = blockIdx.x;
  int t = m >> 6, b = m & 63;
  int idx = seq[b * T_ + t];
  const float4* src = (const float4*)(emb + (size_t)idx * D_);
  float4* dst = (float4*)(x_embed + (size_t)m * D_);
  dst[threadIdx.x] = src[threadIdx.x];
  if (threadIdx.x == 0) actmask[b * T_ + t] = (t < length[b]) ? 1.f : 0.f;
}

// ---------------- feats mean + scope init ----------------
__global__ __launch_bounds__(256) void k_hmean(const float* __restrict__ feats,
    float* __restrict__ hmean, float* __restrict__ scope) {
  int b = blockIdx.x, tid = threadIdx.x;
  for (int e = tid; e < D_; e += 256) {
    float s = 0.f;
    for (int si = 0; si < S_; ++si) s += feats[((size_t)b * S_ + si) * D_ + e];
    hmean[b * D_ + e] = s * (1.f / 49.f);
  }
  if (tid < S_) scope[b * S_ + tid] = 1.f;
}

// ---------------- generic fp32 GEMM: C[M,N] = X[M,K] @ W[N,ldw].T + bias ----------------
__global__ __launch_bounds__(256) void k_gemm_f32(
    float* __restrict__ C, const float* __restrict__ X, const float* __restrict__ W,
    const float* __restrict__ bias, int N, int K, int ldw) {
  __shared__ __align__(16) float XsT[32][68];
  __shared__ __align__(16) float WsT[32][68];
  const int nbase = blockIdx.x * 64, mbase = blockIdx.y * 64;
  const int tid = threadIdx.x;
  const int lr = tid >> 2;
  const int lk = (tid & 3) * 8;
  const int ty = tid >> 4, tx = tid & 15;
  float acc[4][4] = {};
  for (int k0 = 0; k0 < K; k0 += 32) {
    {
      const float* xs = X + (size_t)(mbase + lr) * K + k0 + lk;
      const float* wsrc = W + (size_t)(nbase + lr) * ldw + k0 + lk;
      float4 x0 = *(const float4*)xs, x1 = *(const float4*)(xs + 4);
      float4 w0 = *(const float4*)wsrc, w1 = *(const float4*)(wsrc + 4);
      XsT[lk + 0][lr] = x0.x; XsT[lk + 1][lr] = x0.y; XsT[lk + 2][lr] = x0.z; XsT[lk + 3][lr] = x0.w;
      XsT[lk + 4][lr] = x1.x; XsT[lk + 5][lr] = x1.y; XsT[lk + 6][lr] = x1.z; XsT[lk + 7][lr] = x1.w;
      WsT[lk + 0][lr] = w0.x; WsT[lk + 1][lr] = w0.y; WsT[lk + 2][lr] = w0.z; WsT[lk + 3][lr] = w0.w;
      WsT[lk + 4][lr] = w1.x; WsT[lk + 5][lr] = w1.y; WsT[lk + 6][lr] = w1.z; WsT[lk + 7][lr] = w1.w;
    }
    __syncthreads();
    #pragma unroll
    for (int kk = 0; kk < 32; ++kk) {
      float4 a4 = *(const float4*)&XsT[kk][ty * 4];
      float4 w4 = *(const float4*)&WsT[kk][tx * 4];
      float av[4] = {a4.x, a4.y, a4.z, a4.w};
      float wv[4] = {w4.x, w4.y, w4.z, w4.w};
      #pragma unroll
      for (int i = 0; i < 4; ++i)
        #pragma unroll
        for (int j = 0; j < 4; ++j)
          acc[i][j] = fmaf(av[i], wv[j], acc[i][j]);
    }
    __syncthreads();
  }
  #pragma unroll
  for (int i = 0; i < 4; ++i) {
    int m = mbase + ty * 4 + i;
    int n = nbase + tx * 4;
    float4 o;
    o.x = acc[i][0] + bias[n + 0];
    o.y = acc[i][1] + bias[n + 1];
    o.z = acc[i][2] + bias[n + 2];
    o.w = acc[i][3] + bias[n + 3];
    *(float4*)&C[(size_t)m * N + n] = o;
  }
}

// ---------------- pack kernels (phase A) ----------------
__global__ __launch_bounds__(256) void k_packW(
    const float* __restrict__ Wda, const float* __restrict__ Wbe,
    const float* __restrict__ Whh, const float* __restrict__ Wih,
    f16* __restrict__ Wp1, f16* __restrict__ Wp2) {
  int K = blockIdx.x, tid = threadIdx.x;
  for (int idx = tid; idx < 5120; idx += 256) {
    int s = idx >> 9, e = idx & 511;
    float v;
    if (s < 2)      v = Wda[(size_t)(2 * K + s) * D_ + e];
    else if (s < 4) v = Wbe[(size_t)(2 * K + s - 2) * D_ + e];
    else { int g = (s - 4) >> 1, jj = (s - 4) & 1;
           v = Whh[(size_t)(g * 512 + 2 * K + jj) * D_ + e]; }
    Wp1[(size_t)K * 5120 + idx] = (f16)v;
  }
  for (int idx = tid; idx < 3072; idx += 256) {
    int s = idx >> 9, e = idx & 511;
    int g = s >> 1, jj = s & 1;
    float v = Wih[(size_t)(g * 512 + 2 * K + jj) * 1024 + 512 + e];
    Wp2[(size_t)K * 3072 + idx] = (f16)v;
  }
}

__global__ __launch_bounds__(256) void k_packF(
    const float* __restrict__ feats, const float* __restrict__ att1,
    const float* __restrict__ h0,
    f16* __restrict__ feats16, f16* __restrict__ att116, f16* __restrict__ h16) {
  const int NF = B_ * S_ * D_;
  for (size_t i = blockIdx.x * 256 + threadIdx.x; i < 2 * NF + B_ * D_;
       i += (size_t)gridDim.x * 256) {
    if (i < NF)           feats16[i] = (f16)feats[i];
    else if (i < 2 * NF)  att116[i - NF] = (f16)att1[i - NF];
    else                  h16[i - 2 * NF] = (f16)h0[i - 2 * NF];
  }
}

__global__ __launch_bounds__(256) void k_packG(
    const float* __restrict__ gi_embed, float* __restrict__ gi_pack) {
  for (size_t i = blockIdx.x * 256 + threadIdx.x; i < (size_t)T_ * 256 * 64 * 8;
       i += (size_t)gridDim.x * 256) {
    int slot = i & 7;
    int b = (i >> 3) & 63;
    int K = (i >> 9) & 255;
    int t = i >> 17;
    float v = 0.f;
    if (slot < 6) {
      int g = slot >> 1, jj = slot & 1;
      v = gi_embed[((size_t)t * 64 + b) * G3 + g * 512 + 2 * K + jj];
    }
    gi_pack[i] = v;
  }
}

// -------- fence-free flag sync --------
__device__ __forceinline__ void wait_flags(const int* __restrict__ flags, int n,
                                           int target, int tid, int* ok4) {
  for (;;) {
    bool ok = true;
    if (tid < n)
      ok = (int)ld_a32(flags + tid) >= target;
    bool wok = __all(ok);
    if ((tid & 63) == 0) ok4[tid >> 6] = wok ? 1 : 0;
    __syncthreads();
    bool done = ok4[0] && ok4[1] && ok4[2] && ok4[3];
    __syncthreads();
    if (done) break;
    __builtin_amdgcn_s_sleep(1);
  }
  // no agent fence: all cross-block data moves via relaxed agent atomics (IC);
  // the syncthreads above is the compiler/issue-order barrier.
}

__device__ __forceinline__ void set_flag(int* slot, int val, int tid) {
  __syncthreads();   // compiler emits s_waitcnt vmcnt(0) before s_barrier:
                     // all prior (atomic) data stores are complete at IC
  if (tid == 0) st_a32(slot, (uint32_t)val);
}

// stage 64KB f16 state (h16 or xg16) into swizzled LDS via IC-coherent loads
__device__ __forceinline__ void stage_state(const f16* __restrict__ src,
                                            uint4* __restrict__ hs, int tid) {
  const uint64_t* s64 = (const uint64_t*)src;
  #pragma unroll
  for (int i = 0; i < 32; ++i) {
    int g = i * 256 + tid;          // 8B granule 0..8191
    int b = g >> 7, c8 = g & 127;
    uint64_t v = ld_a64(s64 + g);
    ((uint64_t*)&hs[b * 64 + ((c8 >> 1) ^ (b & 7))])[c8 & 1] = v;
  }
}

// ---------------- persistent recurrence: LDS weights + fence-free IC handoffs ----------------
__global__ __launch_bounds__(256, 1) void k_recur(
    const f16* __restrict__ Wp1, const f16* __restrict__ Wp2,
    const f16* __restrict__ att116, const f16* __restrict__ feats16,
    const float* __restrict__ gi_pack,
    const float* __restrict__ b_da, const float* __restrict__ b_beta,
    const float* __restrict__ b_hh,
    const float* __restrict__ W_fa, const float* __restrict__ b_fa,
    const int* __restrict__ length,
    f16* __restrict__ h16, f16* __restrict__ xg16,
    float* __restrict__ att2g, float* __restrict__ scope,
    float* __restrict__ alphas, f16* __restrict__ Hbuf,
    int* __restrict__ flags) {
  __shared__ __align__(16) uint4 hs[4096];      // 64KB: h or xg staged, swizzled
  __shared__ __align__(16) uint4 W1[1024];      // 16KB
  __shared__ __align__(16) uint4 W2[1024];      // 16KB
  __shared__ float gh_lds[64][6];
  __shared__ float gix_lds[64][6];
  __shared__ float hold_s[64][2];
  __shared__ float att2_s[512];
  __shared__ float gate_s[512];
  __shared__ float att_s[64];
  __shared__ float alpha_s[64];
  __shared__ int ok4[4];

  const int K = blockIdx.x, tid = threadIdx.x;
  const int w = tid >> 6, l = tid & 63;
  const int lm = l & 15, c4 = l >> 4;
  int* flagA = flags;          // [256] att2g/gh ready
  int* flagB = flags + 256;    // [64]  xg ready
  int* flagC = flags + 512;    // [256] h(t+1) ready

  // stage LDS-resident weight slices (once)
  {
    const uint4* s1 = (const uint4*)(Wp1 + (size_t)K * 5120);
    const uint4* s2 = (const uint4*)(Wp2 + (size_t)K * 3072);
    #pragma unroll
    for (int i = 0; i < 3; ++i) {
      int g = i * 256 + tid;
      if (g < 640) { int s = g >> 6, c = g & 63; W1[s * 64 + (c ^ (s & 7))] = s1[g]; }
    }
    #pragma unroll
    for (int i = 0; i < 2; ++i) {
      int g = i * 256 + tid;
      if (g < 384) { int s = g >> 6, c = g & 63; W2[s * 64 + (c ^ (s & 7))] = s2[g]; }
    }
  }
  const int lenP2 = (K < 64) ? length[K] : 0;
  const float bfa0 = b_fa[0];
  int lb = 0;
  float bh[6] = {0.f, 0.f, 0.f, 0.f, 0.f, 0.f};
  if (tid < 64) {
    lb = length[tid];
    #pragma unroll
    for (int s = 0; s < 6; ++s)
      bh[s] = b_hh[(s >> 1) * 512 + 2 * K + (s & 1)];
  }
  __syncthreads();

  for (int t = 0; t < T_; ++t) {
    // ---- wait h(t) ready; stage into LDS (swizzled) ----
    if (t) wait_flags(flagC, 256, t, tid, ok4);
    stage_state(h16, hs, tid);
    __syncthreads();
    // save own j-pair's h(t) before hs is reused for xg
    if (tid < 64) {
      f16x8 hv = __builtin_bit_cast(f16x8, hs[tid * 64 + ((K >> 2) ^ (tid & 7))]);
      int e = (K & 3) * 2;
      hold_s[tid][0] = (float)hv[e];
      hold_s[tid][1] = (float)hv[e + 1];
    }
    // ---- matvec1: [64,512]@[512,16] -> att2g(4, via IC) | gh(6, LDS) ----
    {
      v4f acc = {0.f, 0.f, 0.f, 0.f};
      int bb = w * 16 + lm;
      #pragma unroll
      for (int kt = 0; kt < 16; ++kt) {
        int ca = kt * 4 + c4;
        f16x8 a = __builtin_bit_cast(f16x8, hs[bb * 64 + (ca ^ (bb & 7))]);
        f16x8 bf = __builtin_bit_cast(f16x8, W1[lm * 64 + (ca ^ (lm & 7))]);
        acc = __builtin_amdgcn_mfma_f32_16x16x32_f16(a, bf, acc, 0, 0, 0);
      }
      #pragma unroll
      for (int r = 0; r < 4; ++r) {
        int b = w * 16 + c4 * 4 + r;
        if (lm < 4)
          st_a32((uint32_t*)att2g + b * 1024 + K * 4 + lm,
                 __builtin_bit_cast(uint32_t, acc[r]));
        else if (lm < 10)
          gh_lds[b][lm - 4] = acc[r];
      }
    }
    set_flag(flagA + K, t + 1, tid);
    // ---- P2: attention (blocks 0..63, batch b=K) ----
    if (K < 64) {
      wait_flags(flagA, 256, t + 1, tid, ok4);
      int b = K;
      bool act = t < lenP2;
      const uint64_t* arow2 = (const uint64_t*)att2g + (size_t)b * 512;
      for (int c = tid; c < 512; c += 256) {
        float2 f = __builtin_bit_cast(float2, ld_a64(arow2 + c));
        int a0 = (c >> 1) * 2;
        if (c & 1) {
          gate_s[a0]     = sigm(f.x + b_beta[a0]);
          gate_s[a0 + 1] = sigm(f.y + b_beta[a0 + 1]);
        } else {
          att2_s[a0]     = f.x + b_da[a0];
          att2_s[a0 + 1] = f.y + b_da[a0 + 1];
        }
      }
      __syncthreads();
      int lane = tid & 63, wv = tid >> 6;
      for (int s = wv; s < S_; s += 4) {
        const f16x8* arow = (const f16x8*)(att116 + ((size_t)b * S_ + s) * D_);
        int a0 = lane * 8;
        f16x8 av = arow[lane];
        float p = 0.f;
        #pragma unroll
        for (int jx = 0; jx < 8; ++jx) {
          float v = (float)av[jx] + att2_s[a0 + jx];
          v = v > 0.f ? v : 0.f;
          p = fmaf(v, W_fa[a0 + jx], p);
        }
        #pragma unroll
        for (int off = 32; off > 0; off >>= 1) p += __shfl_xor(p, off, 64);
        if (lane == 0) att_s[s] = p + bfa0;
      }
      __syncthreads();
      if (tid < 64) {
        float x = (tid < S_) ? att_s[tid] : -1e30f;
        float m = x;
        #pragma unroll
        for (int off = 32; off > 0; off >>= 1) m = fmaxf(m, __shfl_xor(m, off, 64));
        float e = (tid < S_) ? __expf(x - m) : 0.f;
        float su = e;
        #pragma unroll
        for (int off = 32; off > 0; off >>= 1) su += __shfl_xor(su, off, 64);
        if (tid < S_) alpha_s[tid] = e / su;
      }
      __syncthreads();
      if (tid < S_) {
        float old = scope[b * S_ + tid], al = alpha_s[tid];
        alphas[((size_t)b * T_ + t) * S_ + tid] = act ? old * al : 0.f;
        scope[b * S_ + tid] = act ? old * (1.f - al) : old;
      }
      if (tid < 128) {
        int e0 = tid * 4;
        float a0 = 0.f, a1 = 0.f, a2 = 0.f, a3 = 0.f;
        #pragma unroll 7
        for (int s = 0; s < S_; ++s) {
          float al = alpha_s[s];
          f16x4 fv = *(const f16x4*)(feats16 + ((size_t)b * S_ + s) * D_ + e0);
          a0 = fmaf(al, (float)fv[0], a0);
          a1 = fmaf(al, (float)fv[1], a1);
          a2 = fmaf(al, (float)fv[2], a2);
          a3 = fmaf(al, (float)fv[3], a3);
        }
        f16x4 o;
        o[0] = (f16)(gate_s[e0 + 0] * a0);
        o[1] = (f16)(gate_s[e0 + 1] * a1);
        o[2] = (f16)(gate_s[e0 + 2] * a2);
        o[3] = (f16)(gate_s[e0 + 3] * a3);
        st_a64((uint64_t*)xg16 + (size_t)b * 128 + tid,
               __builtin_bit_cast(uint64_t, o));
      }
      set_flag(flagB + K, t + 1, tid);
    }
    // ---- wait xg ready; stage into LDS ----
    wait_flags(flagB, 64, t + 1, tid, ok4);
    stage_state(xg16, hs, tid);
    __syncthreads();
    // ---- matvec2: [64,512]@[512,16] -> gix(6, LDS) ----
    {
      v4f acc = {0.f, 0.f, 0.f, 0.f};
      int bb = w * 16 + lm;
      #pragma unroll
      for (int kt = 0; kt < 16; ++kt) {
        int ca = kt * 4 + c4;
        f16x8 a = __builtin_bit_cast(f16x8, hs[bb * 64 + (ca ^ (bb & 7))]);
        f16x8 bf = __builtin_bit_cast(f16x8, W2[lm * 64 + (ca ^ (lm & 7))]);
        acc = __builtin_amdgcn_mfma_f32_16x16x32_f16(a, bf, acc, 0, 0, 0);
      }
      #pragma unroll
      for (int r = 0; r < 4; ++r) {
        int b = w * 16 + c4 * 4 + r;
        if (lm < 6) gix_lds[b][lm] = acc[r];
      }
    }
    __syncthreads();
    // ---- pointwise GRU for own j-pair (both jj per thread, tid<64=batch) ----
    if (tid < 64) {
      int b = tid;
      const float* gp = gi_pack + (((size_t)t * 256 + K) * 64 + b) * 8;
      float r0 = sigm(gix_lds[b][0] + gp[0] + gh_lds[b][0] + bh[0]);
      float r1 = sigm(gix_lds[b][1] + gp[1] + gh_lds[b][1] + bh[1]);
      float z0 = sigm(gix_lds[b][2] + gp[2] + gh_lds[b][2] + bh[2]);
      float z1 = sigm(gix_lds[b][3] + gp[3] + gh_lds[b][3] + bh[3]);
      float n0 = tanhf(gix_lds[b][4] + gp[4] + r0 * (gh_lds[b][4] + bh[4]));
      float n1 = tanhf(gix_lds[b][5] + gp[5] + r1 * (gh_lds[b][5] + bh[5]));
      float hold0 = hold_s[b][0], hold1 = hold_s[b][1];
      float hn0 = (1.f - z0) * n0 + z0 * hold0;
      float hn1 = (1.f - z1) * n1 + z1 * hold1;
      bool act = t < lb;
      unsigned short u0 = __builtin_bit_cast(unsigned short, (f16)(act ? hn0 : hold0));
      unsigned short u1 = __builtin_bit_cast(unsigned short, (f16)(act ? hn1 : hold1));
      st_a32((uint32_t*)h16 + (size_t)b * 256 + K,
             (uint32_t)u0 | ((uint32_t)u1 << 16));
      unsigned short p0 = __builtin_bit_cast(unsigned short, (f16)hn0);
      unsigned short p1 = __builtin_bit_cast(unsigned short, (f16)hn1);
      ((uint32_t*)Hbuf)[((size_t)b * T_ + t) * 256 + K] =
          (uint32_t)p0 | ((uint32_t)p1 << 16);
    }
    set_flag(flagC + K, t + 1, tid);
  }
}

// ---------------- Phase C: out = actmask * (Hbuf @ Wout.T + b_out), f16 MFMA ----------------
__global__ __launch_bounds__(256) void k_outgemm(
    const f16* __restrict__ Hb, const f16* __restrict__ Wb,
    const float* __restrict__ b_out, const float* __restrict__ actmask,
    float* __restrict__ out) {
  __shared__ __align__(16) f16 As[128 * 32];
  __shared__ __align__(16) f16 Bs[128 * 32];
  const int bid = blockIdx.x;
  const int swz = (bid & 7) * 500 + (bid >> 3);
  const int mb = (swz & 15) * 128;
  const int nb = (swz >> 4) * 128;
  const int tid = threadIdx.x;
  const int l = tid & 63, w = tid >> 6;
  const int wr = w >> 1, wc = w & 1;
  const int lm = l & 15;
  const int kc = l >> 4;
  const int rchunk = (kc ^ ((lm >> 1) & 3)) * 8;
  v4f acc[4][4];
  #pragma unroll
  for (int mi = 0; mi < 4; ++mi)
    #pragma unroll
    for (int ni = 0; ni < 4; ++ni)
      acc[mi][ni] = (v4f){0.f, 0.f, 0.f, 0.f};

  for (int k0 = 0; k0 < 512; k0 += 32) {
    #pragma unroll
    for (int i = 0; i < 2; ++i) {
      int ch = i * 256 + tid;
      int row = ch >> 2, cq = ch & 3;
      int sc = (cq ^ ((row >> 1) & 3)) * 8;
      *(int4*)&As[row * 32 + sc] =
          *(const int4*)&Hb[(size_t)(mb + row) * 512 + k0 + cq * 8];
      *(int4*)&Bs[row * 32 + sc] =
          *(const int4*)&Wb[(size_t)(nb + row) * 512 + k0 + cq * 8];
    }
    __syncthreads();
    f16x8 af[4], bf[4];
    #pragma unroll
    for (int mi = 0; mi < 4; ++mi)
      af[mi] = *(const f16x8*)&As[(wr * 64 + mi * 16 + lm) * 32 + rchunk];
    #pragma unroll
    for (int ni = 0; ni < 4; ++ni)
      bf[ni] = *(const f16x8*)&Bs[(wc * 64 + ni * 16 + lm) * 32 + rchunk];
    #pragma unroll
    for (int mi = 0; mi < 4; ++mi)
      #pragma unroll
      for (int ni = 0; ni < 4; ++ni)
        acc[mi][ni] = __builtin_amdgcn_mfma_f32_16x16x32_f16(af[mi], bf[ni], acc[mi][ni], 0, 0, 0);
    __syncthreads();
  }
  #pragma unroll
  for (int ni = 0; ni < 4; ++ni) {
    int n = nb + wc * 64 + ni * 16 + lm;
    float bo = b_out[n];
    #pragma unroll
    for (int mi = 0; mi < 4; ++mi) {
      int m0 = mb + wr * 64 + mi * 16 + (l >> 4) * 4;
      #pragma unroll
      for (int r = 0; r < 4; ++r) {
        int m = m0 + r;
        out[(size_t)m * V_ + n] = actmask[m] * (acc[mi][ni][r] + bo);
      }
    }
  }
}

extern "C" void kernel_launch(void* const* d_in, const int* in_sizes, int n_in,
                              void* d_out, int out_size, void* d_ws, size_t ws_size,
                              hipStream_t stream) {
  const float* feats  = (const float*)d_in[0];
  const int*   seq    = (const int*)d_in[1];
  const int*   length = (const int*)d_in[2];
  const float* emb    = (const float*)d_in[3];
  const float* W_ih   = (const float*)d_in[4];
  const float* b_ih   = (const float*)d_in[5];
  const float* W_hh   = (const float*)d_in[6];
  const float* b_hh   = (const float*)d_in[7];
  const float* W_out  = (const float*)d_in[8];
  const float* b_out  = (const float*)d_in[9];
  const float* W_init = (const float*)d_in[10];
  const float* b_init = (const float*)d_in[11];
  const float* W_beta = (const float*)d_in[12];
  const float* b_beta = (const float*)d_in[13];
  const float* W_ea   = (const float*)d_in[14];
  const float* b_ea   = (const float*)d_in[15];
  const float* W_da   = (const float*)d_in[16];
  const float* b_da   = (const float*)d_in[17];
  const float* W_fa   = (const float*)d_in[18];
  const float* b_fa   = (const float*)d_in[19];

  float* out    = (float*)d_out;
  float* alphas = out + (size_t)B_ * T_ * V_;

  // ---- workspace layout ----
  float* ws = (float*)d_ws;
  int*   flags    = (int*)ws;        ws += 1024;          // A[256] B[64..] C[512..]
  float* h0       = ws;              ws += B_ * D_;
  float* hmean    = ws;              ws += B_ * D_;
  float* scope    = ws;              ws += 4096;
  float* actmask  = ws;              ws += B_ * T_;
  float* att2g    = ws;              ws += B_ * 1024;
  float* x_embed  = ws;              ws += (size_t)B_ * T_ * D_;
  float* gi_embed = ws;              ws += (size_t)B_ * T_ * G3;
  float* gi_pack  = ws;              ws += (size_t)T_ * 256 * 64 * 8;
  float* att1     = ws;              ws += (size_t)B_ * S_ * D_;
  f16* fp = (f16*)ws;
  f16* Woutb   = fp;  fp += (size_t)V_ * D_;
  f16* Hbuf    = fp;  fp += (size_t)B_ * T_ * D_;
  f16* Wp1     = fp;  fp += (size_t)256 * 5120;
  f16* Wp2     = fp;  fp += (size_t)256 * 3072;
  f16* feats16 = fp;  fp += (size_t)B_ * S_ * D_;
  f16* att116  = fp;  fp += (size_t)B_ * S_ * D_;
  f16* h16     = fp;  fp += B_ * D_;
  f16* xg16    = fp;  fp += B_ * D_;

  hipMemsetAsync(flags, 0, 4096, stream);

  // ---- Phase A ----
  k_cvt16<<<(V_ * D_) / 2048, 256, 0, stream>>>(W_out, Woutb);
  k_embed<<<B_ * T_, 128, 0, stream>>>(emb, seq, length, x_embed, actmask);
  k_hmean<<<B_, 256, 0, stream>>>(feats, hmean, scope);
  k_gemm_f32<<<dim3(8, 1), 256, 0, stream>>>(h0, hmean, W_init, b_init, 512, 512, 512);
  k_gemm_f32<<<dim3(8, 49), 256, 0, stream>>>(att1, feats, W_ea, b_ea, 512, 512, 512);
  k_gemm_f32<<<dim3(24, 32), 256, 0, stream>>>(gi_embed, x_embed, W_ih, b_ih, 1536, 512, 1024);
  k_packW<<<256, 256, 0, stream>>>(W_da, W_beta, W_hh, W_ih, Wp1, Wp2);
  k_packF<<<2048, 256, 0, stream>>>(feats, att1, h0, feats16, att116, h16);
  k_packG<<<2048, 256, 0, stream>>>(gi_embed, gi_pack);

  // ---- Phase B: persistent recurrence, fence-free IC handoffs ----
  k_recur<<<NBLK, 256, 0, stream>>>(Wp1, Wp2, att116, feats16, gi_pack,
      b_da, b_beta, b_hh, W_fa, b_fa, length,
      h16, xg16, att2g, scope, alphas, Hbuf, flags);

  // ---- Phase C ----
  k_outgemm<<<4000, 256, 0, stream>>>(Hbuf, Woutb, b_out, actmask, out);
}

// Round 7
// 1610.417 us; speedup vs baseline: 1.8039x; 1.0312x over previous
//
#include <hip/hip_runtime.h>
#include <cstdint>
#include <cstddef>

#define B_   64
#define S_   49
#define T_   32
#define D_   512
#define V_   32000
#define G3   1536
#define NBLK 64

typedef short s16x8 __attribute__((ext_vector_type(8)));
typedef float v4f   __attribute__((ext_vector_type(4)));
typedef _Float16 f16;
typedef _Float16 f16x8 __attribute__((ext_vector_type(8)));
typedef _Float16 f16x4 __attribute__((ext_vector_type(4)));

__device__ __forceinline__ float sigm(float x) { return 1.f / (1.f + __expf(-x)); }

// ---- agent-scope RELAXED atomics: coherent via IC, no L2 maintenance ----
__device__ __forceinline__ uint64_t ld_a64(const void* p) {
  return __hip_atomic_load((const uint64_t*)p, __ATOMIC_RELAXED, __HIP_MEMORY_SCOPE_AGENT);
}
__device__ __forceinline__ void st_a64(void* p, uint64_t v) {
  __hip_atomic_store((uint64_t*)p, v, __ATOMIC_RELAXED, __HIP_MEMORY_SCOPE_AGENT);
}
__device__ __forceinline__ uint32_t ld_a32(const void* p) {
  return __hip_atomic_load((const uint32_t*)p, __ATOMIC_RELAXED, __HIP_MEMORY_SCOPE_AGENT);
}
__device__ __forceinline__ void st_a32(void* p, uint32_t v) {
  __hip_atomic_store((uint32_t*)p, v, __ATOMIC_RELAXED, __HIP_MEMORY_SCOPE_AGENT);
}

// ---------------- fp32 -> f16 conversion ----------------
__global__ __launch_bounds__(256) void k_cvt16(const float* __restrict__ in,
                                               f16* __restrict__ out) {
  int i = (blockIdx.x * 256 + threadIdx.x) * 8;
  float4 a = *(const float4*)(in + i);
  float4 b = *(const float4*)(in + i + 4);
  f16x8 o;
  o[0] = (f16)a.x; o[1] = (f16)a.y; o[2] = (f16)a.z; o[3] = (f16)a.w;
  o[4] = (f16)b.x; o[5] = (f16)b.y; o[6] = (f16)b.z; o[7] = (f16)b.w;
  *(f16x8*)(out + i) = o;
}

// ---------------- embedding gather + active mask ----------------
__global__ __launch_bounds__(128) void k_embed(const float* __restrict__ emb,
    const int* __restrict__ seq, const int* __restrict__ length,
    float* __restrict__ x_embed, float* __restrict__ actmask) {
  int m = blockIdx.x;
  int t = m >> 6, b = m & 63;
  int idx = seq[b * T_ + t];
  const float4* src = (const float4*)(emb + (size_t)idx * D_);
  float4* dst = (float4*)(x_embed + (size_t)m * D_);
  dst[threadIdx.x] = src[threadIdx.x];
  if (threadIdx.x == 0) actmask[b * T_ + t] = (t < length[b]) ? 1.f : 0.f;
}

// ---------------- feats mean ----------------
__global__ __launch_bounds__(256) void k_hmean(const float* __restrict__ feats,
    float* __restrict__ hmean) {
  int b = blockIdx.x, tid = threadIdx.x;
  for (int e = tid; e < D_; e += 256) {
    float s = 0.f;
    for (int si = 0; si < S_; ++si) s += feats[((size_t)b * S_ + si) * D_ + e];
    hmean[b * D_ + e] = s * (1.f / 49.f);
  }
}

// ---------------- generic fp32 GEMM: C[M,N] = X[M,K] @ W[N,ldw].T + bias ----------------
__global__ __launch_bounds__(256) void k_gemm_f32(
    float* __restrict__ C, const float* __restrict__ X, const float* __restrict__ W,
    const float* __restrict__ bias, int N, int K, int ldw) {
  __shared__ __align__(16) float XsT[32][68];
  __shared__ __align__(16) float WsT[32][68];
  const int nbase = blockIdx.x * 64, mbase = blockIdx.y * 64;
  const int tid = threadIdx.x;
  const int lr = tid >> 2;
  const int lk = (tid & 3) * 8;
  const int ty = tid >> 4, tx = tid & 15;
  float acc[4][4] = {};
  for (int k0 = 0; k0 < K; k0 += 32) {
    {
      const float* xs = X + (size_t)(mbase + lr) * K + k0 + lk;
      const float* wsrc = W + (size_t)(nbase + lr) * ldw + k0 + lk;
      float4 x0 = *(const float4*)xs, x1 = *(const float4*)(xs + 4);
      float4 w0 = *(const float4*)wsrc, w1 = *(const float4*)(wsrc + 4);
      XsT[lk + 0][lr] = x0.x; XsT[lk + 1][lr] = x0.y; XsT[lk + 2][lr] = x0.z; XsT[lk + 3][lr] = x0.w;
      XsT[lk + 4][lr] = x1.x; XsT[lk + 5][lr] = x1.y; XsT[lk + 6][lr] = x1.z; XsT[lk + 7][lr] = x1.w;
      WsT[lk + 0][lr] = w0.x; WsT[lk + 1][lr] = w0.y; WsT[lk + 2][lr] = w0.z; WsT[lk + 3][lr] = w0.w;
      WsT[lk + 4][lr] = w1.x; WsT[lk + 5][lr] = w1.y; WsT[lk + 6][lr] = w1.z; WsT[lk + 7][lr] = w1.w;
    }
    __syncthreads();
    #pragma unroll
    for (int kk = 0; kk < 32; ++kk) {
      float4 a4 = *(const float4*)&XsT[kk][ty * 4];
      float4 w4 = *(const float4*)&WsT[kk][tx * 4];
      float av[4] = {a4.x, a4.y, a4.z, a4.w};
      float wv[4] = {w4.x, w4.y, w4.z, w4.w};
      #pragma unroll
      for (int i = 0; i < 4; ++i)
        #pragma unroll
        for (int j = 0; j < 4; ++j)
          acc[i][j] = fmaf(av[i], wv[j], acc[i][j]);
    }
    __syncthreads();
  }
  #pragma unroll
  for (int i = 0; i < 4; ++i) {
    int m = mbase + ty * 4 + i;
    int n = nbase + tx * 4;
    float4 o;
    o.x = acc[i][0] + bias[n + 0];
    o.y = acc[i][1] + bias[n + 1];
    o.z = acc[i][2] + bias[n + 2];
    o.w = acc[i][3] + bias[n + 3];
    *(float4*)&C[(size_t)m * N + n] = o;
  }
}

// ---------------- pack kernels ----------------
// Wp1[K][40][512]: rows 0-7 Wda[8K+r], 8-15 Wbe, 16-23 Whh_r, 24-31 Whh_z, 32-39 Whh_n
// Wp2[K][24][512]: rows 0-7 Wih_r[.., 512:], 8-15 Wih_z, 16-23 Wih_n
__global__ __launch_bounds__(256) void k_packW(
    const float* __restrict__ Wda, const float* __restrict__ Wbe,
    const float* __restrict__ Whh, const float* __restrict__ Wih,
    f16* __restrict__ Wp1, f16* __restrict__ Wp2) {
  int K = blockIdx.x, tid = threadIdx.x;
  for (int idx = tid; idx < 40 * 512; idx += 256) {
    int r = idx >> 9, e = idx & 511;
    float v;
    if (r < 8)       v = Wda[(size_t)(8 * K + r) * D_ + e];
    else if (r < 16) v = Wbe[(size_t)(8 * K + r - 8) * D_ + e];
    else if (r < 24) v = Whh[(size_t)(8 * K + r - 16) * D_ + e];
    else if (r < 32) v = Whh[(size_t)(512 + 8 * K + r - 24) * D_ + e];
    else             v = Whh[(size_t)(1024 + 8 * K + r - 32) * D_ + e];
    Wp1[(size_t)K * 20480 + idx] = (f16)v;
  }
  for (int idx = tid; idx < 24 * 512; idx += 256) {
    int r = idx >> 9, e = idx & 511;
    int g = r >> 3, jj = r & 7;
    float v = Wih[(size_t)(g * 512 + 8 * K + jj) * 1024 + 512 + e];
    Wp2[(size_t)K * 12288 + idx] = (f16)v;
  }
}

__global__ __launch_bounds__(256) void k_packF(
    const float* __restrict__ feats, const float* __restrict__ att1,
    const float* __restrict__ h0,
    f16* __restrict__ feats16, f16* __restrict__ att116, f16* __restrict__ h16) {
  const int NF = B_ * S_ * D_;
  for (size_t i = blockIdx.x * 256 + threadIdx.x; i < 2 * NF + B_ * D_;
       i += (size_t)gridDim.x * 256) {
    if (i < NF)           feats16[i] = (f16)feats[i];
    else if (i < 2 * NF)  att116[i - NF] = (f16)att1[i - NF];
    else                  h16[i - 2 * NF] = (f16)h0[i - 2 * NF];
  }
}

// gi_pack[((t*64+K)*32 + slot)*64 + b], slot = gate*8+jj (24 used, 32 padded)
__global__ __launch_bounds__(256) void k_packG(
    const float* __restrict__ gi_embed, float* __restrict__ gi_pack) {
  for (size_t i = blockIdx.x * 256 + threadIdx.x; i < (size_t)T_ * 64 * 32 * 64;
       i += (size_t)gridDim.x * 256) {
    int b = i & 63;
    int slot = (i >> 6) & 31;
    int Kb = (i >> 11) & 63;
    int t = i >> 17;
    if (slot < 24) {
      int g8 = slot >> 3, jj = slot & 7;
      gi_pack[i] = gi_embed[((size_t)t * 64 + b) * G3 + g8 * 512 + 8 * Kb + jj];
    }
  }
}

// -------- fence-free flag sync (R6-proven) --------
__device__ __forceinline__ void wait_flags(const int* __restrict__ flags, int n,
                                           int target, int tid, int* ok4) {
  for (;;) {
    bool ok = true;
    if (tid < n)
      ok = (int)ld_a32(flags + tid) >= target;
    bool wok = __all(ok);
    if ((tid & 63) == 0) ok4[tid >> 6] = wok ? 1 : 0;
    __syncthreads();
    bool done = ok4[0] && ok4[1] && ok4[2] && ok4[3];
    __syncthreads();
    if (done) break;
    __builtin_amdgcn_s_sleep(1);
  }
}

__device__ __forceinline__ void set_flag(int* slot, int val, int tid) {
  __syncthreads();   // vmcnt(0) before s_barrier: prior data stores complete
  if (tid == 0) st_a32(slot, (uint32_t)val);
}

// stage 64KB f16 state into swizzled LDS via IC-coherent loads
__device__ __forceinline__ void stage_state(const f16* __restrict__ src,
                                            uint4* __restrict__ hs, int tid) {
  const uint64_t* s64 = (const uint64_t*)src;
  #pragma unroll
  for (int i = 0; i < 32; ++i) {
    int g = i * 256 + tid;
    int b = g >> 7, c8 = g & 127;
    uint64_t v = ld_a64(s64 + g);
    ((uint64_t*)&hs[b * 64 + ((c8 >> 1) ^ (b & 7))])[c8 & 1] = v;
  }
}

// ---------------- persistent recurrence: 64 blocks, block K owns j in [8K,8K+8) ----------------
// + batch K's attention. 4x less IC broadcast traffic than 256-block R6.
__global__ __launch_bounds__(256, 1) void k_recur(
    const f16* __restrict__ Wp1, const f16* __restrict__ Wp2,
    const f16* __restrict__ att116, const f16* __restrict__ feats16,
    const float* __restrict__ gi_pack,
    const float* __restrict__ b_da, const float* __restrict__ b_beta,
    const float* __restrict__ b_hh,
    const float* __restrict__ W_fa, const float* __restrict__ b_fa,
    const int* __restrict__ length,
    f16* __restrict__ h16, f16* __restrict__ xg16,
    float* __restrict__ att2g,
    float* __restrict__ alphas, f16* __restrict__ Hbuf,
    int* __restrict__ flags) {
  // LDS carve: hs 4096u4 (64KB) | W1 2560u4 (40 rows) | W2 1536u4 (24 rows) | 512u4 pad
  // (W1 tile2 reads rows 40-47 -> lands in W2; W2 tile1 reads rows 24-31 -> pad; garbage discarded)
  __shared__ __align__(16) uint4 lds_all[8704];
  __shared__ float gh_lds[24 * 72];    // stride 72: bank-spread
  __shared__ float gix_lds[24 * 72];
  __shared__ float att2_s[512];
  __shared__ float gate_s[512];
  __shared__ float att_s[64];
  __shared__ float alpha_s[64];
  __shared__ int ok4[4];
  uint4* hs = lds_all;
  uint4* W1 = lds_all + 4096;
  uint4* W2 = lds_all + 6656;

  const int K = blockIdx.x, tid = threadIdx.x;
  const int w = tid >> 6, l = tid & 63;
  const int lm = l & 15, c4 = l >> 4;
  const int bq = tid & 63, jg = tid >> 6;       // pointwise mapping
  const int jj0 = 2 * jg, jj1 = 2 * jg + 1;
  int* flagA = flags;
  int* flagB = flags + 256;
  int* flagC = flags + 512;

  // stage LDS-resident weights (once)
  {
    const uint4* s1 = (const uint4*)(Wp1 + (size_t)K * 20480);
    const uint4* s2 = (const uint4*)(Wp2 + (size_t)K * 12288);
    #pragma unroll
    for (int i = 0; i < 10; ++i) {
      int g = i * 256 + tid;
      int s = g >> 6, c = g & 63;
      W1[s * 64 + (c ^ (s & 7))] = s1[g];
    }
    #pragma unroll
    for (int i = 0; i < 6; ++i) {
      int g = i * 256 + tid;
      int s = g >> 6, c = g & 63;
      W2[s * 64 + (c ^ (s & 7))] = s2[g];
    }
  }
  const int lenB = length[K];
  const float bfa0 = b_fa[0];
  const int lb = length[bq];
  const float bhr0 = b_hh[8 * K + jj0],        bhr1 = b_hh[8 * K + jj1];
  const float bhz0 = b_hh[512 + 8 * K + jj0],  bhz1 = b_hh[512 + 8 * K + jj1];
  const float bhn0 = b_hh[1024 + 8 * K + jj0], bhn1 = b_hh[1024 + 8 * K + jj1];
  float scope_r = 1.f;
  __syncthreads();

  for (int t = 0; t < T_; ++t) {
    // ---- wait h(t); stage ----
    if (t) wait_flags(flagC, 64, t, tid, ok4);
    stage_state(h16, hs, tid);
    __syncthreads();
    // save h_old for own j-pair (the block's 8 j's live in granule cq==K)
    float hold0, hold1;
    {
      f16x8 hv = __builtin_bit_cast(f16x8, hs[bq * 64 + (K ^ (bq & 7))]);
      hold0 = (float)hv[jj0]; hold1 = (float)hv[jj1];
    }
    // ---- matvec1: h @ W1 -> att2/gate (global) + ghr/ghz/ghn (LDS) ----
    {
      v4f a0 = {0.f,0.f,0.f,0.f}, a1 = {0.f,0.f,0.f,0.f}, a2 = {0.f,0.f,0.f,0.f};
      int bb = w * 16 + lm;
      #pragma unroll
      for (int kt = 0; kt < 16; ++kt) {
        int ca = kt * 4 + c4;
        f16x8 av = __builtin_bit_cast(f16x8, hs[bb * 64 + (ca ^ (bb & 7))]);
        f16x8 b0 = __builtin_bit_cast(f16x8, W1[lm * 64 + (ca ^ (lm & 7))]);
        f16x8 b1 = __builtin_bit_cast(f16x8, W1[(16 + lm) * 64 + (ca ^ ((16 + lm) & 7))]);
        f16x8 b2 = __builtin_bit_cast(f16x8, W1[(32 + lm) * 64 + (ca ^ ((32 + lm) & 7))]);
        a0 = __builtin_amdgcn_mfma_f32_16x16x32_f16(av, b0, a0, 0, 0, 0);
        a1 = __builtin_amdgcn_mfma_f32_16x16x32_f16(av, b1, a1, 0, 0, 0);
        a2 = __builtin_amdgcn_mfma_f32_16x16x32_f16(av, b2, a2, 0, 0, 0);
      }
      #pragma unroll
      for (int r = 0; r < 4; ++r) {
        int bat = w * 16 + c4 * 4 + r;
        int col = (lm < 8) ? (8 * K + lm) : (512 + 8 * K + lm - 8);
        st_a32((uint32_t*)att2g + bat * 1024 + col, __builtin_bit_cast(uint32_t, a0[r]));
        gh_lds[lm * 72 + bat] = a1[r];
        if (lm < 8) gh_lds[(16 + lm) * 72 + bat] = a2[r];
      }
    }
    set_flag(flagA + K, t + 1, tid);
    wait_flags(flagA, 64, t + 1, tid, ok4);
    // ---- attention for batch K ----
    {
      bool act = t < lenB;
      const uint64_t* arow2 = (const uint64_t*)att2g + (size_t)K * 512;
      for (int c = tid; c < 512; c += 256) {
        float2 f = __builtin_bit_cast(float2, ld_a64(arow2 + c));
        int a0i = 2 * c;
        if (a0i < 512) {
          att2_s[a0i]     = f.x + b_da[a0i];
          att2_s[a0i + 1] = f.y + b_da[a0i + 1];
        } else {
          int gi = a0i - 512;
          gate_s[gi]     = sigm(f.x + b_beta[gi]);
          gate_s[gi + 1] = sigm(f.y + b_beta[gi + 1]);
        }
      }
      __syncthreads();
      for (int s = w; s < S_; s += 4) {
        const f16x8* arow = (const f16x8*)(att116 + ((size_t)K * S_ + s) * D_);
        int a0i = l * 8;
        f16x8 av = arow[l];
        float p = 0.f;
        #pragma unroll
        for (int jx = 0; jx < 8; ++jx) {
          float v = (float)av[jx] + att2_s[a0i + jx];
          v = v > 0.f ? v : 0.f;
          p = fmaf(v, W_fa[a0i + jx], p);
        }
        #pragma unroll
        for (int off = 32; off > 0; off >>= 1) p += __shfl_xor(p, off, 64);
        if (l == 0) att_s[s] = p + bfa0;
      }
      __syncthreads();
      if (tid < 64) {
        float x = (tid < S_) ? att_s[tid] : -1e30f;
        float m = x;
        #pragma unroll
        for (int off = 32; off > 0; off >>= 1) m = fmaxf(m, __shfl_xor(m, off, 64));
        float e = (tid < S_) ? __expf(x - m) : 0.f;
        float su = e;
        #pragma unroll
        for (int off = 32; off > 0; off >>= 1) su += __shfl_xor(su, off, 64);
        if (tid < S_) alpha_s[tid] = e / su;
      }
      __syncthreads();
      if (tid < S_) {
        float al = alpha_s[tid];
        alphas[((size_t)K * T_ + t) * S_ + tid] = act ? scope_r * al : 0.f;
        scope_r = act ? scope_r * (1.f - al) : scope_r;
      }
      if (tid < 128) {
        int e0 = tid * 4;
        float s0 = 0.f, s1 = 0.f, s2 = 0.f, s3 = 0.f;
        #pragma unroll 7
        for (int s = 0; s < S_; ++s) {
          float al = alpha_s[s];
          f16x4 fv = *(const f16x4*)(feats16 + ((size_t)K * S_ + s) * D_ + e0);
          s0 = fmaf(al, (float)fv[0], s0);
          s1 = fmaf(al, (float)fv[1], s1);
          s2 = fmaf(al, (float)fv[2], s2);
          s3 = fmaf(al, (float)fv[3], s3);
        }
        f16x4 o;
        o[0] = (f16)(gate_s[e0 + 0] * s0);
        o[1] = (f16)(gate_s[e0 + 1] * s1);
        o[2] = (f16)(gate_s[e0 + 2] * s2);
        o[3] = (f16)(gate_s[e0 + 3] * s3);
        st_a64((uint64_t*)xg16 + (size_t)K * 128 + tid,
               __builtin_bit_cast(uint64_t, o));
      }
    }
    set_flag(flagB + K, t + 1, tid);
    wait_flags(flagB, 64, t + 1, tid, ok4);
    stage_state(xg16, hs, tid);
    __syncthreads();
    // ---- matvec2: xg @ W2 -> gixr/gixz/gixn (LDS) ----
    {
      v4f c0 = {0.f,0.f,0.f,0.f}, c1 = {0.f,0.f,0.f,0.f};
      int bb = w * 16 + lm;
      #pragma unroll
      for (int kt = 0; kt < 16; ++kt) {
        int ca = kt * 4 + c4;
        f16x8 av = __builtin_bit_cast(f16x8, hs[bb * 64 + (ca ^ (bb & 7))]);
        f16x8 b0 = __builtin_bit_cast(f16x8, W2[lm * 64 + (ca ^ (lm & 7))]);
        f16x8 b1 = __builtin_bit_cast(f16x8, W2[(16 + lm) * 64 + (ca ^ ((16 + lm) & 7))]);
        c0 = __builtin_amdgcn_mfma_f32_16x16x32_f16(av, b0, c0, 0, 0, 0);
        c1 = __builtin_amdgcn_mfma_f32_16x16x32_f16(av, b1, c1, 0, 0, 0);
      }
      #pragma unroll
      for (int r = 0; r < 4; ++r) {
        int bat = w * 16 + c4 * 4 + r;
        gix_lds[lm * 72 + bat] = c0[r];
        if (lm < 8) gix_lds[(16 + lm) * 72 + bat] = c1[r];
      }
    }
    __syncthreads();
    // ---- pointwise GRU: thread (bq, jg) owns j = 8K+2jg, 8K+2jg+1 ----
    {
      const float* gp = gi_pack + (size_t)(t * 64 + K) * 2048;  // 32 slots * 64 b
      float r0 = sigm(gix_lds[jj0 * 72 + bq] + gp[jj0 * 64 + bq] + gh_lds[jj0 * 72 + bq] + bhr0);
      float r1 = sigm(gix_lds[jj1 * 72 + bq] + gp[jj1 * 64 + bq] + gh_lds[jj1 * 72 + bq] + bhr1);
      float z0 = sigm(gix_lds[(8 + jj0) * 72 + bq] + gp[(8 + jj0) * 64 + bq] + gh_lds[(8 + jj0) * 72 + bq] + bhz0);
      float z1 = sigm(gix_lds[(8 + jj1) * 72 + bq] + gp[(8 + jj1) * 64 + bq] + gh_lds[(8 + jj1) * 72 + bq] + bhz1);
      float n0 = tanhf(gix_lds[(16 + jj0) * 72 + bq] + gp[(16 + jj0) * 64 + bq] + r0 * (gh_lds[(16 + jj0) * 72 + bq] + bhn0));
      float n1 = tanhf(gix_lds[(16 + jj1) * 72 + bq] + gp[(16 + jj1) * 64 + bq] + r1 * (gh_lds[(16 + jj1) * 72 + bq] + bhn1));
      float hn0 = (1.f - z0) * n0 + z0 * hold0;
      float hn1 = (1.f - z1) * n1 + z1 * hold1;
      bool act = t < lb;
      unsigned short u0 = __builtin_bit_cast(unsigned short, (f16)(act ? hn0 : hold0));
      unsigned short u1 = __builtin_bit_cast(unsigned short, (f16)(act ? hn1 : hold1));
      st_a32((uint32_t*)h16 + bq * 256 + 4 * K + jg,
             (uint32_t)u0 | ((uint32_t)u1 << 16));
      unsigned short p0 = __builtin_bit_cast(unsigned short, (f16)hn0);
      unsigned short p1 = __builtin_bit_cast(unsigned short, (f16)hn1);
      ((uint32_t*)Hbuf)[((size_t)bq * T_ + t) * 256 + 4 * K + jg] =
          (uint32_t)p0 | ((uint32_t)p1 << 16);
    }
    set_flag(flagC + K, t + 1, tid);
  }
}

// ---------------- Phase C: out = actmask * (Hbuf @ Wout.T + b_out), f16 MFMA ----------------
__global__ __launch_bounds__(256) void k_outgemm(
    const f16* __restrict__ Hb, const f16* __restrict__ Wb,
    const float* __restrict__ b_out, const float* __restrict__ actmask,
    float* __restrict__ out) {
  __shared__ __align__(16) f16 As[128 * 32];
  __shared__ __align__(16) f16 Bs[128 * 32];
  const int bid = blockIdx.x;
  const int swz = (bid & 7) * 500 + (bid >> 3);
  const int mb = (swz & 15) * 128;
  const int nb = (swz >> 4) * 128;
  const int tid = threadIdx.x;
  const int l = tid & 63, w = tid >> 6;
  const int wr = w >> 1, wc = w & 1;
  const int lm = l & 15;
  const int kc = l >> 4;
  const int rchunk = (kc ^ ((lm >> 1) & 3)) * 8;
  v4f acc[4][4];
  #pragma unroll
  for (int mi = 0; mi < 4; ++mi)
    #pragma unroll
    for (int ni = 0; ni < 4; ++ni)
      acc[mi][ni] = (v4f){0.f, 0.f, 0.f, 0.f};

  for (int k0 = 0; k0 < 512; k0 += 32) {
    #pragma unroll
    for (int i = 0; i < 2; ++i) {
      int ch = i * 256 + tid;
      int row = ch >> 2, cq = ch & 3;
      int sc = (cq ^ ((row >> 1) & 3)) * 8;
      *(int4*)&As[row * 32 + sc] =
          *(const int4*)&Hb[(size_t)(mb + row) * 512 + k0 + cq * 8];
      *(int4*)&Bs[row * 32 + sc] =
          *(const int4*)&Wb[(size_t)(nb + row) * 512 + k0 + cq * 8];
    }
    __syncthreads();
    f16x8 af[4], bf[4];
    #pragma unroll
    for (int mi = 0; mi < 4; ++mi)
      af[mi] = *(const f16x8*)&As[(wr * 64 + mi * 16 + lm) * 32 + rchunk];
    #pragma unroll
    for (int ni = 0; ni < 4; ++ni)
      bf[ni] = *(const f16x8*)&Bs[(wc * 64 + ni * 16 + lm) * 32 + rchunk];
    #pragma unroll
    for (int mi = 0; mi < 4; ++mi)
      #pragma unroll
      for (int ni = 0; ni < 4; ++ni)
        acc[mi][ni] = __builtin_amdgcn_mfma_f32_16x16x32_f16(af[mi], bf[ni], acc[mi][ni], 0, 0, 0);
    __syncthreads();
  }
  #pragma unroll
  for (int ni = 0; ni < 4; ++ni) {
    int n = nb + wc * 64 + ni * 16 + lm;
    float bo = b_out[n];
    #pragma unroll
    for (int mi = 0; mi < 4; ++mi) {
      int m0 = mb + wr * 64 + mi * 16 + (l >> 4) * 4;
      #pragma unroll
      for (int r = 0; r < 4; ++r) {
        int m = m0 + r;
        out[(size_t)m * V_ + n] = actmask[m] * (acc[mi][ni][r] + bo);
      }
    }
  }
}

extern "C" void kernel_launch(void* const* d_in, const int* in_sizes, int n_in,
                              void* d_out, int out_size, void* d_ws, size_t ws_size,
                              hipStream_t stream) {
  const float* feats  = (const float*)d_in[0];
  const int*   seq    = (const int*)d_in[1];
  const int*   length = (const int*)d_in[2];
  const float* emb    = (const float*)d_in[3];
  const float* W_ih   = (const float*)d_in[4];
  const float* b_ih   = (const float*)d_in[5];
  const float* W_hh   = (const float*)d_in[6];
  const float* b_hh   = (const float*)d_in[7];
  const float* W_out  = (const float*)d_in[8];
  const float* b_out  = (const float*)d_in[9];
  const float* W_init = (const float*)d_in[10];
  const float* b_init = (const float*)d_in[11];
  const float* W_beta = (const float*)d_in[12];
  const float* b_beta = (const float*)d_in[13];
  const float* W_ea   = (const float*)d_in[14];
  const float* b_ea   = (const float*)d_in[15];
  const float* W_da   = (const float*)d_in[16];
  const float* b_da   = (const float*)d_in[17];
  const float* W_fa   = (const float*)d_in[18];
  const float* b_fa   = (const float*)d_in[19];

  float* out    = (float*)d_out;
  float* alphas = out + (size_t)B_ * T_ * V_;

  // ---- workspace layout ----
  float* ws = (float*)d_ws;
  int*   flags    = (int*)ws;        ws += 1024;
  float* h0       = ws;              ws += B_ * D_;
  float* hmean    = ws;              ws += B_ * D_;
  float* actmask  = ws;              ws += B_ * T_;
  float* att2g    = ws;              ws += B_ * 1024;
  float* x_embed  = ws;              ws += (size_t)B_ * T_ * D_;
  float* gi_embed = ws;              ws += (size_t)B_ * T_ * G3;
  float* gi_pack  = ws;              ws += (size_t)T_ * 64 * 32 * 64;
  float* att1     = ws;              ws += (size_t)B_ * S_ * D_;
  f16* fp = (f16*)ws;
  f16* Woutb   = fp;  fp += (size_t)V_ * D_;
  f16* Hbuf    = fp;  fp += (size_t)B_ * T_ * D_;
  f16* Wp1     = fp;  fp += (size_t)64 * 20480;
  f16* Wp2     = fp;  fp += (size_t)64 * 12288;
  f16* feats16 = fp;  fp += (size_t)B_ * S_ * D_;
  f16* att116  = fp;  fp += (size_t)B_ * S_ * D_;
  f16* h16     = fp;  fp += B_ * D_;
  f16* xg16    = fp;  fp += B_ * D_;

  hipMemsetAsync(flags, 0, 4096, stream);

  // ---- Phase A ----
  k_cvt16<<<(V_ * D_) / 2048, 256, 0, stream>>>(W_out, Woutb);
  k_embed<<<B_ * T_, 128, 0, stream>>>(emb, seq, length, x_embed, actmask);
  k_hmean<<<B_, 256, 0, stream>>>(feats, hmean);
  k_gemm_f32<<<dim3(8, 1), 256, 0, stream>>>(h0, hmean, W_init, b_init, 512, 512, 512);
  k_gemm_f32<<<dim3(8, 49), 256, 0, stream>>>(att1, feats, W_ea, b_ea, 512, 512, 512);
  k_gemm_f32<<<dim3(24, 32), 256, 0, stream>>>(gi_embed, x_embed, W_ih, b_ih, 1536, 512, 1024);
  k_packW<<<64, 256, 0, stream>>>(W_da, W_beta, W_hh, W_ih, Wp1, Wp2);
  k_packF<<<2048, 256, 0, stream>>>(feats, att1, h0, feats16, att116, h16);
  k_packG<<<2048, 256, 0, stream>>>(gi_embed, gi_pack);

  // ---- Phase B: persistent recurrence, 64 blocks ----
  k_recur<<<NBLK, 256, 0, stream>>>(Wp1, Wp2, att116, feats16, gi_pack,
      b_da, b_beta, b_hh, W_fa, b_fa, length,
      h16, xg16, att2g, alphas, Hbuf, flags);

  // ---- Phase C ----
  k_outgemm<<<4000, 256, 0, stream>>>(Hbuf, Woutb, b_out, actmask, out);
}

// Round 8
// 1496.016 us; speedup vs baseline: 1.9418x; 1.0765x over previous
//
#include <hip/hip_runtime.h>
#include <cstdint>
#include <cstddef>

#define B_   64
#define S_   49
#define T_   32
#define D_   512
#define V_   32000
#define G3   1536
#define NBLK 64

typedef short s16x8 __attribute__((ext_vector_type(8)));
typedef float v4f   __attribute__((ext_vector_type(4)));
typedef _Float16 f16;
typedef _Float16 f16x8 __attribute__((ext_vector_type(8)));
typedef _Float16 f16x4 __attribute__((ext_vector_type(4)));

__device__ __forceinline__ float sigm(float x) { return 1.f / (1.f + __expf(-x)); }

// ---- agent-scope RELAXED atomics: coherent via IC, no L2 maintenance ----
__device__ __forceinline__ uint64_t ld_a64(const void* p) {
  return __hip_atomic_load((const uint64_t*)p, __ATOMIC_RELAXED, __HIP_MEMORY_SCOPE_AGENT);
}
__device__ __forceinline__ void st_a64(void* p, uint64_t v) {
  __hip_atomic_store((uint64_t*)p, v, __ATOMIC_RELAXED, __HIP_MEMORY_SCOPE_AGENT);
}
__device__ __forceinline__ uint32_t ld_a32(const void* p) {
  return __hip_atomic_load((const uint32_t*)p, __ATOMIC_RELAXED, __HIP_MEMORY_SCOPE_AGENT);
}
__device__ __forceinline__ void st_a32(void* p, uint32_t v) {
  __hip_atomic_store((uint32_t*)p, v, __ATOMIC_RELAXED, __HIP_MEMORY_SCOPE_AGENT);
}

// ---------------- fp32 -> f16 conversion ----------------
__global__ __launch_bounds__(256) void k_cvt16(const float* __restrict__ in,
                                               f16* __restrict__ out) {
  int i = (blockIdx.x * 256 + threadIdx.x) * 8;
  float4 a = *(const float4*)(in + i);
  float4 b = *(const float4*)(in + i + 4);
  f16x8 o;
  o[0] = (f16)a.x; o[1] = (f16)a.y; o[2] = (f16)a.z; o[3] = (f16)a.w;
  o[4] = (f16)b.x; o[5] = (f16)b.y; o[6] = (f16)b.z; o[7] = (f16)b.w;
  *(f16x8*)(out + i) = o;
}

// ---------------- embedding gather + active mask ----------------
__global__ __launch_bounds__(128) void k_embed(const float* __restrict__ emb,
    const int* __restrict__ seq, const int* __restrict__ length,
    float* __restrict__ x_embed, float* __restrict__ actmask) {
  int m = blockIdx.x;
  int t = m >> 6, b = m & 63;
  int idx = seq[b * T_ + t];
  const float4* src = (const float4*)(emb + (size_t)idx * D_);
  float4* dst = (float4*)(x_embed + (size_t)m * D_);
  dst[threadIdx.x] = src[threadIdx.x];
  if (threadIdx.x == 0) actmask[b * T_ + t] = (t < length[b]) ? 1.f : 0.f;
}

// ---------------- feats mean ----------------
__global__ __launch_bounds__(256) void k_hmean(const float* __restrict__ feats,
    float* __restrict__ hmean) {
  int b = blockIdx.x, tid = threadIdx.x;
  for (int e = tid; e < D_; e += 256) {
    float s = 0.f;
    for (int si = 0; si < S_; ++si) s += feats[((size_t)b * S_ + si) * D_ + e];
    hmean[b * D_ + e] = s * (1.f / 49.f);
  }
}

// ---------------- generic fp32 GEMM: C[M,N] = X[M,K] @ W[N,ldw].T + bias ----------------
__global__ __launch_bounds__(256) void k_gemm_f32(
    float* __restrict__ C, const float* __restrict__ X, const float* __restrict__ W,
    const float* __restrict__ bias, int N, int K, int ldw) {
  __shared__ __align__(16) float XsT[32][68];
  __shared__ __align__(16) float WsT[32][68];
  const int nbase = blockIdx.x * 64, mbase = blockIdx.y * 64;
  const int tid = threadIdx.x;
  const int lr = tid >> 2;
  const int lk = (tid & 3) * 8;
  const int ty = tid >> 4, tx = tid & 15;
  float acc[4][4] = {};
  for (int k0 = 0; k0 < K; k0 += 32) {
    {
      const float* xs = X + (size_t)(mbase + lr) * K + k0 + lk;
      const float* wsrc = W + (size_t)(nbase + lr) * ldw + k0 + lk;
      float4 x0 = *(const float4*)xs, x1 = *(const float4*)(xs + 4);
      float4 w0 = *(const float4*)wsrc, w1 = *(const float4*)(wsrc + 4);
      XsT[lk + 0][lr] = x0.x; XsT[lk + 1][lr] = x0.y; XsT[lk + 2][lr] = x0.z; XsT[lk + 3][lr] = x0.w;
      XsT[lk + 4][lr] = x1.x; XsT[lk + 5][lr] = x1.y; XsT[lk + 6][lr] = x1.z; XsT[lk + 7][lr] = x1.w;
      WsT[lk + 0][lr] = w0.x; WsT[lk + 1][lr] = w0.y; WsT[lk + 2][lr] = w0.z; WsT[lk + 3][lr] = w0.w;
      WsT[lk + 4][lr] = w1.x; WsT[lk + 5][lr] = w1.y; WsT[lk + 6][lr] = w1.z; WsT[lk + 7][lr] = w1.w;
    }
    __syncthreads();
    #pragma unroll
    for (int kk = 0; kk < 32; ++kk) {
      float4 a4 = *(const float4*)&XsT[kk][ty * 4];
      float4 w4 = *(const float4*)&WsT[kk][tx * 4];
      float av[4] = {a4.x, a4.y, a4.z, a4.w};
      float wv[4] = {w4.x, w4.y, w4.z, w4.w};
      #pragma unroll
      for (int i = 0; i < 4; ++i)
        #pragma unroll
        for (int j = 0; j < 4; ++j)
          acc[i][j] = fmaf(av[i], wv[j], acc[i][j]);
    }
    __syncthreads();
  }
  #pragma unroll
  for (int i = 0; i < 4; ++i) {
    int m = mbase + ty * 4 + i;
    int n = nbase + tx * 4;
    float4 o;
    o.x = acc[i][0] + bias[n + 0];
    o.y = acc[i][1] + bias[n + 1];
    o.z = acc[i][2] + bias[n + 2];
    o.w = acc[i][3] + bias[n + 3];
    *(float4*)&C[(size_t)m * N + n] = o;
  }
}

// ---------------- pack kernels ----------------
// Wp1[K][40][512]: rows 0-7 Wda[8K+r], 8-15 Wbe, 16-23 Whh_r, 24-31 Whh_z, 32-39 Whh_n
// Wp2[K][24][512]: rows 0-7 Wih_r[.., 512:], 8-15 Wih_z, 16-23 Wih_n
__global__ __launch_bounds__(256) void k_packW(
    const float* __restrict__ Wda, const float* __restrict__ Wbe,
    const float* __restrict__ Whh, const float* __restrict__ Wih,
    f16* __restrict__ Wp1, f16* __restrict__ Wp2) {
  int K = blockIdx.x, tid = threadIdx.x;
  for (int idx = tid; idx < 40 * 512; idx += 256) {
    int r = idx >> 9, e = idx & 511;
    float v;
    if (r < 8)       v = Wda[(size_t)(8 * K + r) * D_ + e];
    else if (r < 16) v = Wbe[(size_t)(8 * K + r - 8) * D_ + e];
    else if (r < 24) v = Whh[(size_t)(8 * K + r - 16) * D_ + e];
    else if (r < 32) v = Whh[(size_t)(512 + 8 * K + r - 24) * D_ + e];
    else             v = Whh[(size_t)(1024 + 8 * K + r - 32) * D_ + e];
    Wp1[(size_t)K * 20480 + idx] = (f16)v;
  }
  for (int idx = tid; idx < 24 * 512; idx += 256) {
    int r = idx >> 9, e = idx & 511;
    int g = r >> 3, jj = r & 7;
    float v = Wih[(size_t)(g * 512 + 8 * K + jj) * 1024 + 512 + e];
    Wp2[(size_t)K * 12288 + idx] = (f16)v;
  }
}

__global__ __launch_bounds__(256) void k_packF(
    const float* __restrict__ feats, const float* __restrict__ att1,
    const float* __restrict__ h0,
    f16* __restrict__ feats16, f16* __restrict__ att116, f16* __restrict__ h16) {
  const int NF = B_ * S_ * D_;
  for (size_t i = blockIdx.x * 256 + threadIdx.x; i < 2 * NF + B_ * D_;
       i += (size_t)gridDim.x * 256) {
    if (i < NF)           feats16[i] = (f16)feats[i];
    else if (i < 2 * NF)  att116[i - NF] = (f16)att1[i - NF];
    else                  h16[i - 2 * NF] = (f16)h0[i - 2 * NF];
  }
}

// gi_pack[((t*64+K)*32 + slot)*64 + b], slot = gate*8+jj (24 used, 32 padded)
__global__ __launch_bounds__(256) void k_packG(
    const float* __restrict__ gi_embed, float* __restrict__ gi_pack) {
  for (size_t i = blockIdx.x * 256 + threadIdx.x; i < (size_t)T_ * 64 * 32 * 64;
       i += (size_t)gridDim.x * 256) {
    int b = i & 63;
    int slot = (i >> 6) & 31;
    int Kb = (i >> 11) & 63;
    int t = i >> 17;
    if (slot < 24) {
      int g8 = slot >> 3, jj = slot & 7;
      gi_pack[i] = gi_embed[((size_t)t * 64 + b) * G3 + g8 * 512 + 8 * Kb + jj];
    }
  }
}

// -------- R8 sync: 64B-padded flags + single-wave barrier-free poll --------
// R7 post-mortem: ~10us/sync across two mechanisms = poll contention (4096
// uncoalesced atomic loads/round on 4 cache lines) + 2 block barriers/round.
// Now: flag k lives on its own 64B line (flags[k*16]); only wave 0 polls
// (1 VMEM instr/round, 64 distinct lines); waves 1-3 park at one barrier.
__device__ __forceinline__ void wait_flags64(const int* __restrict__ flags,
                                             int target, int tid) {
  if (tid < 64) {
    while (!__all((int)ld_a32(flags + tid * 16) >= target))
      __builtin_amdgcn_s_sleep(2);
  }
  __syncthreads();
}

__device__ __forceinline__ void set_flag(int* slot, int val, int tid) {
  __syncthreads();   // vmcnt(0) before s_barrier: prior data stores complete
  if (tid == 0) st_a32(slot, (uint32_t)val);
}

// stage 64KB f16 state into swizzled LDS via IC-coherent loads
__device__ __forceinline__ void stage_state(const f16* __restrict__ src,
                                            uint4* __restrict__ hs, int tid) {
  const uint64_t* s64 = (const uint64_t*)src;
  #pragma unroll
  for (int i = 0; i < 32; ++i) {
    int g = i * 256 + tid;
    int b = g >> 7, c8 = g & 127;
    uint64_t v = ld_a64(s64 + g);
    ((uint64_t*)&hs[b * 64 + ((c8 >> 1) ^ (b & 7))])[c8 & 1] = v;
  }
}

// ---------------- persistent recurrence: 64 blocks, block K owns j in [8K,8K+8) ----------------
__global__ __launch_bounds__(256, 1) void k_recur(
    const f16* __restrict__ Wp1, const f16* __restrict__ Wp2,
    const f16* __restrict__ att116, const f16* __restrict__ feats16,
    const float* __restrict__ gi_pack,
    const float* __restrict__ b_da, const float* __restrict__ b_beta,
    const float* __restrict__ b_hh,
    const float* __restrict__ W_fa, const float* __restrict__ b_fa,
    const int* __restrict__ length,
    f16* __restrict__ h16, f16* __restrict__ xg16,
    float* __restrict__ att2g,
    float* __restrict__ alphas, f16* __restrict__ Hbuf,
    int* __restrict__ flags) {
  // LDS carve: hs 4096u4 (64KB) | W1 2560u4 | W2 1536u4 | pad 512u4 (8KB)
  // pad doubles as: W2 garbage-read area (rows 24-31, discarded) + attp[64][16]
  __shared__ __align__(16) uint4 lds_all[8704];
  __shared__ float gh_lds[24 * 72];
  __shared__ float gix_lds[24 * 72];
  __shared__ float att2_s[512];
  __shared__ float gate_s[512];
  __shared__ float att_s[64];
  __shared__ float alpha_s[64];
  uint4* hs = lds_all;
  uint4* W1 = lds_all + 4096;
  uint4* W2 = lds_all + 6656;
  float* attp = (float*)(lds_all + 8192);   // 4KB of the pad

  const int K = blockIdx.x, tid = threadIdx.x;
  const int w = tid >> 6, l = tid & 63;
  const int lm = l & 15, c4 = l >> 4;
  const int bq = tid & 63, jg = tid >> 6;
  const int jj0 = 2 * jg, jj1 = 2 * jg + 1;
  int* flagA = flags;              // [64] x 16-int stride
  int* flagB = flags + 1024;
  int* flagC = flags + 2048;

  // stage LDS-resident weights (once)
  {
    const uint4* s1 = (const uint4*)(Wp1 + (size_t)K * 20480);
    const uint4* s2 = (const uint4*)(Wp2 + (size_t)K * 12288);
    #pragma unroll
    for (int i = 0; i < 10; ++i) {
      int g = i * 256 + tid;
      int s = g >> 6, c = g & 63;
      W1[s * 64 + (c ^ (s & 7))] = s1[g];
    }
    #pragma unroll
    for (int i = 0; i < 6; ++i) {
      int g = i * 256 + tid;
      int s = g >> 6, c = g & 63;
      W2[s * 64 + (c ^ (s & 7))] = s2[g];
    }
  }
  const int lenB = length[K];
  const float bfa0 = b_fa[0];
  const int lb = length[bq];
  const float bhr0 = b_hh[8 * K + jj0],        bhr1 = b_hh[8 * K + jj1];
  const float bhz0 = b_hh[512 + 8 * K + jj0],  bhz1 = b_hh[512 + 8 * K + jj1];
  const float bhn0 = b_hh[1024 + 8 * K + jj0], bhn1 = b_hh[1024 + 8 * K + jj1];
  float scope_r = 1.f;
  __syncthreads();

  for (int t = 0; t < T_; ++t) {
    // ---- wait h(t); stage ----
    if (t) wait_flags64(flagC, t, tid);
    stage_state(h16, hs, tid);
    __syncthreads();
    float hold0, hold1;
    {
      f16x8 hv = __builtin_bit_cast(f16x8, hs[bq * 64 + (K ^ (bq & 7))]);
      hold0 = (float)hv[jj0]; hold1 = (float)hv[jj1];
    }
    // ---- matvec1: h @ W1 -> attp (LDS) + gh (LDS) ----
    {
      v4f a0 = {0.f,0.f,0.f,0.f}, a1 = {0.f,0.f,0.f,0.f}, a2 = {0.f,0.f,0.f,0.f};
      int bb = w * 16 + lm;
      #pragma unroll
      for (int kt = 0; kt < 16; ++kt) {
        int ca = kt * 4 + c4;
        f16x8 av = __builtin_bit_cast(f16x8, hs[bb * 64 + (ca ^ (bb & 7))]);
        f16x8 b0 = __builtin_bit_cast(f16x8, W1[lm * 64 + (ca ^ (lm & 7))]);
        f16x8 b1 = __builtin_bit_cast(f16x8, W1[(16 + lm) * 64 + (ca ^ ((16 + lm) & 7))]);
        f16x8 b2 = __builtin_bit_cast(f16x8, W1[(32 + lm) * 64 + (ca ^ ((32 + lm) & 7))]);
        a0 = __builtin_amdgcn_mfma_f32_16x16x32_f16(av, b0, a0, 0, 0, 0);
        a1 = __builtin_amdgcn_mfma_f32_16x16x32_f16(av, b1, a1, 0, 0, 0);
        a2 = __builtin_amdgcn_mfma_f32_16x16x32_f16(av, b2, a2, 0, 0, 0);
      }
      #pragma unroll
      for (int r = 0; r < 4; ++r) {
        int bat = w * 16 + c4 * 4 + r;
        attp[bat * 16 + lm] = a0[r];
        gh_lds[lm * 72 + bat] = a1[r];
        if (lm < 8) gh_lds[(16 + lm) * 72 + bat] = a2[r];
      }
    }
    __syncthreads();
    // ---- pack att2g stores to 8B (512 transactions instead of 1024) ----
    #pragma unroll
    for (int q = 0; q < 2; ++q) {
      int pp = tid * 2 + q;            // 0..511
      int bat = pp >> 3, pi = pp & 7;
      float2 f2;
      f2.x = attp[bat * 16 + 2 * pi];
      f2.y = attp[bat * 16 + 2 * pi + 1];
      size_t idx = (size_t)bat * 512 +
                   ((pi < 4) ? (4 * K + pi) : (256 + 4 * K + (pi - 4)));
      st_a64((uint64_t*)att2g + idx, __builtin_bit_cast(uint64_t, f2));
    }
    set_flag(flagA + K * 16, t + 1, tid);
    wait_flags64(flagA, t + 1, tid);
    // ---- attention for batch K ----
    {
      bool act = t < lenB;
      const uint64_t* arow2 = (const uint64_t*)att2g + (size_t)K * 512;
      for (int c = tid; c < 512; c += 256) {
        float2 f = __builtin_bit_cast(float2, ld_a64(arow2 + c));
        int a0i = 2 * c;
        if (a0i < 512) {
          att2_s[a0i]     = f.x + b_da[a0i];
          att2_s[a0i + 1] = f.y + b_da[a0i + 1];
        } else {
          int gi = a0i - 512;
          gate_s[gi]     = sigm(f.x + b_beta[gi]);
          gate_s[gi + 1] = sigm(f.y + b_beta[gi + 1]);
        }
      }
      __syncthreads();
      for (int s = w; s < S_; s += 4) {
        const f16x8* arow = (const f16x8*)(att116 + ((size_t)K * S_ + s) * D_);
        int a0i = l * 8;
        f16x8 av = arow[l];
        float p = 0.f;
        #pragma unroll
        for (int jx = 0; jx < 8; ++jx) {
          float v = (float)av[jx] + att2_s[a0i + jx];
          v = v > 0.f ? v : 0.f;
          p = fmaf(v, W_fa[a0i + jx], p);
        }
        #pragma unroll
        for (int off = 32; off > 0; off >>= 1) p += __shfl_xor(p, off, 64);
        if (l == 0) att_s[s] = p + bfa0;
      }
      __syncthreads();
      if (tid < 64) {
        float x = (tid < S_) ? att_s[tid] : -1e30f;
        float m = x;
        #pragma unroll
        for (int off = 32; off > 0; off >>= 1) m = fmaxf(m, __shfl_xor(m, off, 64));
        float e = (tid < S_) ? __expf(x - m) : 0.f;
        float su = e;
        #pragma unroll
        for (int off = 32; off > 0; off >>= 1) su += __shfl_xor(su, off, 64);
        if (tid < S_) alpha_s[tid] = e / su;
      }
      __syncthreads();
      if (tid < S_) {
        float al = alpha_s[tid];
        alphas[((size_t)K * T_ + t) * S_ + tid] = act ? scope_r * al : 0.f;
        scope_r = act ? scope_r * (1.f - al) : scope_r;
      }
      if (tid < 128) {
        int e0 = tid * 4;
        float s0 = 0.f, s1 = 0.f, s2 = 0.f, s3 = 0.f;
        #pragma unroll 7
        for (int s = 0; s < S_; ++s) {
          float al = alpha_s[s];
          f16x4 fv = *(const f16x4*)(feats16 + ((size_t)K * S_ + s) * D_ + e0);
          s0 = fmaf(al, (float)fv[0], s0);
          s1 = fmaf(al, (float)fv[1], s1);
          s2 = fmaf(al, (float)fv[2], s2);
          s3 = fmaf(al, (float)fv[3], s3);
        }
        f16x4 o;
        o[0] = (f16)(gate_s[e0 + 0] * s0);
        o[1] = (f16)(gate_s[e0 + 1] * s1);
        o[2] = (f16)(gate_s[e0 + 2] * s2);
        o[3] = (f16)(gate_s[e0 + 3] * s3);
        st_a64((uint64_t*)xg16 + (size_t)K * 128 + tid,
               __builtin_bit_cast(uint64_t, o));
      }
    }
    set_flag(flagB + K * 16, t + 1, tid);
    wait_flags64(flagB, t + 1, tid);
    stage_state(xg16, hs, tid);
    __syncthreads();
    // ---- matvec2: xg @ W2 -> gix (LDS) ----
    {
      v4f c0 = {0.f,0.f,0.f,0.f}, c1 = {0.f,0.f,0.f,0.f};
      int bb = w * 16 + lm;
      #pragma unroll
      for (int kt = 0; kt < 16; ++kt) {
        int ca = kt * 4 + c4;
        f16x8 av = __builtin_bit_cast(f16x8, hs[bb * 64 + (ca ^ (bb & 7))]);
        f16x8 b0 = __builtin_bit_cast(f16x8, W2[lm * 64 + (ca ^ (lm & 7))]);
        f16x8 b1 = __builtin_bit_cast(f16x8, W2[(16 + lm) * 64 + (ca ^ ((16 + lm) & 7))]);
        c0 = __builtin_amdgcn_mfma_f32_16x16x32_f16(av, b0, c0, 0, 0, 0);
        c1 = __builtin_amdgcn_mfma_f32_16x16x32_f16(av, b1, c1, 0, 0, 0);
      }
      #pragma unroll
      for (int r = 0; r < 4; ++r) {
        int bat = w * 16 + c4 * 4 + r;
        gix_lds[lm * 72 + bat] = c0[r];
        if (lm < 8) gix_lds[(16 + lm) * 72 + bat] = c1[r];
      }
    }
    __syncthreads();
    // ---- pointwise GRU: thread (bq, jg) owns j = 8K+2jg, 8K+2jg+1 ----
    {
      const float* gp = gi_pack + (size_t)(t * 64 + K) * 2048;
      float r0 = sigm(gix_lds[jj0 * 72 + bq] + gp[jj0 * 64 + bq] + gh_lds[jj0 * 72 + bq] + bhr0);
      float r1 = sigm(gix_lds[jj1 * 72 + bq] + gp[jj1 * 64 + bq] + gh_lds[jj1 * 72 + bq] + bhr1);
      float z0 = sigm(gix_lds[(8 + jj0) * 72 + bq] + gp[(8 + jj0) * 64 + bq] + gh_lds[(8 + jj0) * 72 + bq] + bhz0);
      float z1 = sigm(gix_lds[(8 + jj1) * 72 + bq] + gp[(8 + jj1) * 64 + bq] + gh_lds[(8 + jj1) * 72 + bq] + bhz1);
      float n0 = tanhf(gix_lds[(16 + jj0) * 72 + bq] + gp[(16 + jj0) * 64 + bq] + r0 * (gh_lds[(16 + jj0) * 72 + bq] + bhn0));
      float n1 = tanhf(gix_lds[(16 + jj1) * 72 + bq] + gp[(16 + jj1) * 64 + bq] + r1 * (gh_lds[(16 + jj1) * 72 + bq] + bhn1));
      float hn0 = (1.f - z0) * n0 + z0 * hold0;
      float hn1 = (1.f - z1) * n1 + z1 * hold1;
      bool act = t < lb;
      unsigned short u0 = __builtin_bit_cast(unsigned short, (f16)(act ? hn0 : hold0));
      unsigned short u1 = __builtin_bit_cast(unsigned short, (f16)(act ? hn1 : hold1));
      st_a32((uint32_t*)h16 + bq * 256 + 4 * K + jg,
             (uint32_t)u0 | ((uint32_t)u1 << 16));
      unsigned short p0 = __builtin_bit_cast(unsigned short, (f16)hn0);
      unsigned short p1 = __builtin_bit_cast(unsigned short, (f16)hn1);
      ((uint32_t*)Hbuf)[((size_t)bq * T_ + t) * 256 + 4 * K + jg] =
          (uint32_t)p0 | ((uint32_t)p1 << 16);
    }
    set_flag(flagC + K * 16, t + 1, tid);
  }
}

// ---------------- Phase C: out = actmask * (Hbuf @ Wout.T + b_out), f16 MFMA ----------------
__global__ __launch_bounds__(256) void k_outgemm(
    const f16* __restrict__ Hb, const f16* __restrict__ Wb,
    const float* __restrict__ b_out, const float* __restrict__ actmask,
    float* __restrict__ out) {
  __shared__ __align__(16) f16 As[128 * 32];
  __shared__ __align__(16) f16 Bs[128 * 32];
  const int bid = blockIdx.x;
  const int swz = (bid & 7) * 500 + (bid >> 3);
  const int mb = (swz & 15) * 128;
  const int nb = (swz >> 4) * 128;
  const int tid = threadIdx.x;
  const int l = tid & 63, w = tid >> 6;
  const int wr = w >> 1, wc = w & 1;
  const int lm = l & 15;
  const int kc = l >> 4;
  const int rchunk = (kc ^ ((lm >> 1) & 3)) * 8;
  v4f acc[4][4];
  #pragma unroll
  for (int mi = 0; mi < 4; ++mi)
    #pragma unroll
    for (int ni = 0; ni < 4; ++ni)
      acc[mi][ni] = (v4f){0.f, 0.f, 0.f, 0.f};

  for (int k0 = 0; k0 < 512; k0 += 32) {
    #pragma unroll
    for (int i = 0; i < 2; ++i) {
      int ch = i * 256 + tid;
      int row = ch >> 2, cq = ch & 3;
      int sc = (cq ^ ((row >> 1) & 3)) * 8;
      *(int4*)&As[row * 32 + sc] =
          *(const int4*)&Hb[(size_t)(mb + row) * 512 + k0 + cq * 8];
      *(int4*)&Bs[row * 32 + sc] =
          *(const int4*)&Wb[(size_t)(nb + row) * 512 + k0 + cq * 8];
    }
    __syncthreads();
    f16x8 af[4], bf[4];
    #pragma unroll
    for (int mi = 0; mi < 4; ++mi)
      af[mi] = *(const f16x8*)&As[(wr * 64 + mi * 16 + lm) * 32 + rchunk];
    #pragma unroll
    for (int ni = 0; ni < 4; ++ni)
      bf[ni] = *(const f16x8*)&Bs[(wc * 64 + ni * 16 + lm) * 32 + rchunk];
    #pragma unroll
    for (int mi = 0; mi < 4; ++mi)
      #pragma unroll
      for (int ni = 0; ni < 4; ++ni)
        acc[mi][ni] = __builtin_amdgcn_mfma_f32_16x16x32_f16(af[mi], bf[ni], acc[mi][ni], 0, 0, 0);
    __syncthreads();
  }
  #pragma unroll
  for (int ni = 0; ni < 4; ++ni) {
    int n = nb + wc * 64 + ni * 16 + lm;
    float bo = b_out[n];
    #pragma unroll
    for (int mi = 0; mi < 4; ++mi) {
      int m0 = mb + wr * 64 + mi * 16 + (l >> 4) * 4;
      #pragma unroll
      for (int r = 0; r < 4; ++r) {
        int m = m0 + r;
        out[(size_t)m * V_ + n] = actmask[m] * (acc[mi][ni][r] + bo);
      }
    }
  }
}

extern "C" void kernel_launch(void* const* d_in, const int* in_sizes, int n_in,
                              void* d_out, int out_size, void* d_ws, size_t ws_size,
                              hipStream_t stream) {
  const float* feats  = (const float*)d_in[0];
  const int*   seq    = (const int*)d_in[1];
  const int*   length = (const int*)d_in[2];
  const float* emb    = (const float*)d_in[3];
  const float* W_ih   = (const float*)d_in[4];
  const float* b_ih   = (const float*)d_in[5];
  const float* W_hh   = (const float*)d_in[6];
  const float* b_hh   = (const float*)d_in[7];
  const float* W_out  = (const float*)d_in[8];
  const float* b_out  = (const float*)d_in[9];
  const float* W_init = (const float*)d_in[10];
  const float* b_init = (const float*)d_in[11];
  const float* W_beta = (const float*)d_in[12];
  const float* b_beta = (const float*)d_in[13];
  const float* W_ea   = (const float*)d_in[14];
  const float* b_ea   = (const float*)d_in[15];
  const float* W_da   = (const float*)d_in[16];
  const float* b_da   = (const float*)d_in[17];
  const float* W_fa   = (const float*)d_in[18];
  const float* b_fa   = (const float*)d_in[19];

  float* out    = (float*)d_out;
  float* alphas = out + (size_t)B_ * T_ * V_;

  // ---- workspace layout ----
  float* ws = (float*)d_ws;
  int*   flags    = (int*)ws;        ws += 4096;  // 3 x 64 flags, 64B stride
  float* h0       = ws;              ws += B_ * D_;
  float* hmean    = ws;              ws += B_ * D_;
  float* actmask  = ws;              ws += B_ * T_;
  float* att2g    = ws;              ws += B_ * 1024;
  float* x_embed  = ws;              ws += (size_t)B_ * T_ * D_;
  float* gi_embed = ws;              ws += (size_t)B_ * T_ * G3;
  float* gi_pack  = ws;              ws += (size_t)T_ * 64 * 32 * 64;
  float* att1     = ws;              ws += (size_t)B_ * S_ * D_;
  f16* fp = (f16*)ws;
  f16* Woutb   = fp;  fp += (size_t)V_ * D_;
  f16* Hbuf    = fp;  fp += (size_t)B_ * T_ * D_;
  f16* Wp1     = fp;  fp += (size_t)64 * 20480;
  f16* Wp2     = fp;  fp += (size_t)64 * 12288;
  f16* feats16 = fp;  fp += (size_t)B_ * S_ * D_;
  f16* att116  = fp;  fp += (size_t)B_ * S_ * D_;
  f16* h16     = fp;  fp += B_ * D_;
  f16* xg16    = fp;  fp += B_ * D_;

  hipMemsetAsync(flags, 0, 16384, stream);

  // ---- Phase A ----
  k_cvt16<<<(V_ * D_) / 2048, 256, 0, stream>>>(W_out, Woutb);
  k_embed<<<B_ * T_, 128, 0, stream>>>(emb, seq, length, x_embed, actmask);
  k_hmean<<<B_, 256, 0, stream>>>(feats, hmean);
  k_gemm_f32<<<dim3(8, 1), 256, 0, stream>>>(h0, hmean, W_init, b_init, 512, 512, 512);
  k_gemm_f32<<<dim3(8, 49), 256, 0, stream>>>(att1, feats, W_ea, b_ea, 512, 512, 512);
  k_gemm_f32<<<dim3(24, 32), 256, 0, stream>>>(gi_embed, x_embed, W_ih, b_ih, 1536, 512, 1024);
  k_packW<<<64, 256, 0, stream>>>(W_da, W_beta, W_hh, W_ih, Wp1, Wp2);
  k_packF<<<2048, 256, 0, stream>>>(feats, att1, h0, feats16, att116, h16);
  k_packG<<<2048, 256, 0, stream>>>(gi_embed, gi_pack);

  // ---- Phase B: persistent recurrence, 64 blocks, lean sync ----
  k_recur<<<NBLK, 256, 0, stream>>>(Wp1, Wp2, att116, feats16, gi_pack,
      b_da, b_beta, b_hh, W_fa, b_fa, length,
      h16, xg16, att2g, alphas, Hbuf, flags);

  // ---- Phase C ----
  k_outgemm<<<4000, 256, 0, stream>>>(Hbuf, Woutb, b_out, actmask, out);
}